// Round 3
// baseline (1398.628 us; speedup 1.0000x reference)
//
#include <hip/hip_runtime.h>
#include <math.h>
#include <stdint.h>

constexpr int NNODES = 50000;
constexpr int NEDGES = 400000;
constexpr int INF = 1433;
constexpr int KP1 = 1440;          // INF padded to multiple of 32
constexpr int HID = 384;
constexpr int EMB = 256;
constexpr int NCLS = 7;

typedef __attribute__((ext_vector_type(8))) short bf16x8_t;   // 8 bf16 in 4 VGPRs
typedef __attribute__((ext_vector_type(4))) float f32x4_t;    // MFMA accumulator

// ---------------------------------------------------------------- degrees
__global__ void degree_kernel(const int* __restrict__ src, const int* __restrict__ dst,
                              int* __restrict__ dout, int* __restrict__ din, int E) {
  int i = blockIdx.x * blockDim.x + threadIdx.x;
  int stride = gridDim.x * blockDim.x;
  for (; i < E; i += stride) {
    atomicAdd(&dout[src[i]], 1);
    atomicAdd(&din[dst[i]], 1);
  }
}

__global__ void inv_kernel(const int* __restrict__ dout, const int* __restrict__ din,
                           float* __restrict__ inv_s, float* __restrict__ inv_d, int N) {
  int i = blockIdx.x * blockDim.x + threadIdx.x;
  if (i < N) {
    inv_s[i] = 1.0f / sqrtf(fmaxf((float)dout[i], 1.0f));
    inv_d[i] = 1.0f / sqrtf(fmaxf((float)din[i], 1.0f));
  }
}

// ---------------------------------------------------------------- exclusive scan (CSR offsets)
__global__ __launch_bounds__(1024)
void scan_kernel(const int* __restrict__ deg, int* __restrict__ off, int N) {
  __shared__ int buf[1024];
  __shared__ int carry;
  if (threadIdx.x == 0) carry = 0;
  __syncthreads();
  for (int base = 0; base < N; base += 1024) {
    int i = base + threadIdx.x;
    int v = (i < N) ? deg[i] : 0;
    buf[threadIdx.x] = v;
    __syncthreads();
    #pragma unroll
    for (int d = 1; d < 1024; d <<= 1) {
      int t = (threadIdx.x >= d) ? buf[threadIdx.x - d] : 0;
      __syncthreads();
      buf[threadIdx.x] += t;
      __syncthreads();
    }
    if (i < N) off[i] = carry + buf[threadIdx.x] - v;  // exclusive
    __syncthreads();
    if (threadIdx.x == 1023) carry += buf[1023];
    __syncthreads();
  }
  if (threadIdx.x == 0) off[N] = carry;
}

__global__ void fill_csr(const int* __restrict__ src, const int* __restrict__ dst,
                         const int* __restrict__ off, int* __restrict__ cursor,
                         int* __restrict__ csr_src, int E) {
  int i = blockIdx.x * blockDim.x + threadIdx.x;
  int stride = gridDim.x * blockDim.x;
  for (; i < E; i += stride) {
    int d = dst[i];
    int p = atomicAdd(&cursor[d], 1);
    csr_src[off[d] + p] = src[i];
  }
}

// ---------------------------------------------------------------- W1 split+transpose
// W [K][Nn] fp32  ->  Bt_hi/Bt_lo [Nn][Kp] bf16 (truncation split, zero-padded tail)
__global__ void split_transpose(const float* __restrict__ W, ushort* __restrict__ bt_hi,
                                ushort* __restrict__ bt_lo, int K, int Nn, int Kp) {
  int k = blockIdx.x * 256 + threadIdx.x;
  int n = blockIdx.y;
  if (k >= Kp) return;
  float v = (k < K) ? W[(size_t)k * Nn + n] : 0.f;
  uint32_t u = __float_as_uint(v);
  float hiF = __uint_as_float(u & 0xFFFF0000u);
  uint32_t u2 = __float_as_uint(v - hiF);
  bt_hi[(size_t)n * Kp + k] = (ushort)(u >> 16);
  bt_lo[(size_t)n * Kp + k] = (ushort)(u2 >> 16);
}

// ---------------------------------------------------------------- split-bf16 MFMA GEMM (layer 1)
// C[M,Nn] = (A_f32[M,K] @ Bt^T) * scale[row], via 3-term split: ah*bh + ah*bl + al*bh
// 128x128 tile, 4 waves, each wave 64x64 (4x4 frags of 16x16x32). 2 barriers/K-step.
__global__ __launch_bounds__(256, 2)
void gemm1_mfma(const float* __restrict__ A, const ushort* __restrict__ bt_hi,
                const ushort* __restrict__ bt_lo, float* __restrict__ C,
                const float* __restrict__ scale, int M, int Nn, int K, int Kp)
{
  // sA: interleaved dword per element = hi_u16 | lo_u16<<16, rows 128B, XOR-swizzled
  // sB: two bf16 planes [128 cols][32 kk], rows 64B (conflict-free without swizzle)
  __shared__ __align__(16) uint32_t sA[128 * 32];
  __shared__ __align__(16) uint32_t sB[128 * 32];
  char* sAB  = (char*)sA;
  char* sBhi = (char*)sB;
  char* sBlo = sBhi + 8192;

  const int tid = threadIdx.x;
  const int row0 = blockIdx.y * 128;
  const int col0 = blockIdx.x * 128;
  const int l = tid & 63;
  const int w = tid >> 6;
  const int wr = w >> 1, wc = w & 1;          // wave quadrant (2x2 of 64x64)
  const int lane15 = l & 15, kg = l >> 4;     // frag row/col & k-group

  f32x4_t acc[4][4];
  #pragma unroll
  for (int mi = 0; mi < 4; ++mi)
    #pragma unroll
    for (int ni = 0; ni < 4; ++ni) acc[mi][ni] = {0.f, 0.f, 0.f, 0.f};

  for (int kt = 0; kt < Kp; kt += 32) {
    // ---- load A elements (coalesced dwords; K odd -> 4B align only) + truncation split
    uint32_t av[16];
    #pragma unroll
    for (int i = 0; i < 16; ++i) {
      int ra = (tid >> 5) + i * 8;
      int kk = tid & 31;
      int gr = row0 + ra, gk = kt + kk;
      float v = 0.f;
      if (gr < M && gk < K) v = A[(size_t)gr * K + gk];
      uint32_t u = __float_as_uint(v);
      float hiF = __uint_as_float(u & 0xFFFF0000u);
      uint32_t u2 = __float_as_uint(v - hiF);
      av[i] = (u2 & 0xFFFF0000u) | (u >> 16);     // lo<<16 | hi
    }
    // ---- load B tile (bf16 planes, 16B vectors)
    uint4 bv[4];
    #pragma unroll
    for (int i = 0; i < 4; ++i) {
      int cid = tid + 256 * i;
      int plane = cid >> 9, c = (cid >> 2) & 127, q = cid & 3;
      const ushort* src = plane ? bt_lo : bt_hi;
      bv[i] = *(const uint4*)(src + (size_t)(col0 + c) * Kp + kt + q * 8);
    }
    __syncthreads();   // previous iteration's frag reads done
    #pragma unroll
    for (int i = 0; i < 16; ++i) {
      int ra = (tid >> 5) + i * 8;
      int kk = tid & 31;
      int bo = (ra * 128 + kk * 4) ^ ((ra & 7) << 4);   // XOR swizzle (G4)
      *(uint32_t*)(sAB + bo) = av[i];
    }
    #pragma unroll
    for (int i = 0; i < 4; ++i) {
      int cid = tid + 256 * i;
      int plane = cid >> 9, c = (cid >> 2) & 127, q = cid & 3;
      *(uint4*)((plane ? sBlo : sBhi) + c * 64 + q * 16) = bv[i];
    }
    __syncthreads();   // staging visible

    // ---- fragments: B contiguous b128; A two b128 + hi/lo unzip (compiler -> v_perm)
    bf16x8_t bh[4], bl[4], ah[4], al[4];
    #pragma unroll
    for (int ni = 0; ni < 4; ++ni) {
      int off = (wc * 64 + ni * 16 + lane15) * 64 + kg * 16;
      bh[ni] = *(const bf16x8_t*)(sBhi + off);
      bl[ni] = *(const bf16x8_t*)(sBlo + off);
    }
    #pragma unroll
    for (int mi = 0; mi < 4; ++mi) {
      int ra = wr * 64 + mi * 16 + lane15;
      int a0 = (ra * 128 + kg * 32) ^ ((ra & 7) << 4);
      uint4 d0 = *(const uint4*)(sAB + a0);
      uint4 d1 = *(const uint4*)(sAB + (a0 ^ 16));
      union { uint32_t u[4]; bf16x8_t v; } th, tl;
      th.u[0] = (d0.x & 0xFFFFu) | (d0.y << 16);
      th.u[1] = (d0.z & 0xFFFFu) | (d0.w << 16);
      th.u[2] = (d1.x & 0xFFFFu) | (d1.y << 16);
      th.u[3] = (d1.z & 0xFFFFu) | (d1.w << 16);
      tl.u[0] = (d0.x >> 16) | (d0.y & 0xFFFF0000u);
      tl.u[1] = (d0.z >> 16) | (d0.w & 0xFFFF0000u);
      tl.u[2] = (d1.x >> 16) | (d1.y & 0xFFFF0000u);
      tl.u[3] = (d1.z >> 16) | (d1.w & 0xFFFF0000u);
      ah[mi] = th.v; al[mi] = tl.v;
    }
    #pragma unroll
    for (int mi = 0; mi < 4; ++mi)
      #pragma unroll
      for (int ni = 0; ni < 4; ++ni) {
        acc[mi][ni] = __builtin_amdgcn_mfma_f32_16x16x32_bf16(ah[mi], bh[ni], acc[mi][ni], 0, 0, 0);
        acc[mi][ni] = __builtin_amdgcn_mfma_f32_16x16x32_bf16(ah[mi], bl[ni], acc[mi][ni], 0, 0, 0);
        acc[mi][ni] = __builtin_amdgcn_mfma_f32_16x16x32_bf16(al[mi], bh[ni], acc[mi][ni], 0, 0, 0);
      }
  }

  // ---- epilogue: D row=(l>>4)*4+j, col=l&15 (m89-verified); scale rows by inv_s
  #pragma unroll
  for (int mi = 0; mi < 4; ++mi) {
    #pragma unroll
    for (int j = 0; j < 4; ++j) {
      int gr = row0 + wr * 64 + mi * 16 + kg * 4 + j;
      if (gr >= M) continue;
      float s = scale[gr];
      #pragma unroll
      for (int ni = 0; ni < 4; ++ni) {
        int gc = col0 + wc * 64 + ni * 16 + lane15;
        C[(size_t)gr * Nn + gc] = acc[mi][ni][j] * s;
      }
    }
  }
}

// ---------------------------------------------------------------- fp32 GEMM (layer 2)
template<int BK>
__global__ __launch_bounds__(256)
void gemm_scale(const float* __restrict__ A, const float* __restrict__ B,
                float* __restrict__ C, const float* __restrict__ scale,
                int M, int N, int K)
{
  constexpr int BM = 128, BN = 128;
  constexpr int LDA = BM + 4;
  constexpr int LDB = BN + 4;
  __shared__ float As[BK][LDA];
  __shared__ float Bs[BK][LDB];

  const int tid = threadIdx.x;
  const int tx = tid & 15;
  const int ty = tid >> 4;
  const int row0 = blockIdx.y * BM;
  const int col0 = blockIdx.x * BN;

  float acc[8][8];
  #pragma unroll
  for (int i = 0; i < 8; ++i)
    #pragma unroll
    for (int j = 0; j < 8; ++j) acc[i][j] = 0.f;

  for (int kt = 0; kt < K; kt += BK) {
    #pragma unroll
    for (int p = 0; p < BM / 16; ++p) {
      int r = (tid >> 4) + p * 16;
      int k = tid & 15;
      int gr = row0 + r, gk = kt + k;
      float v = 0.f;
      if (gr < M && gk < K) v = A[(size_t)gr * K + gk];
      As[k][r] = v;
    }
    #pragma unroll
    for (int p = 0; p < BK / 8; ++p) {
      int r = (tid >> 5) + p * 8;
      int c4 = (tid & 31) * 4;
      int gk = kt + r;
      float4 v = {0.f, 0.f, 0.f, 0.f};
      if (gk < K) v = *(const float4*)&B[(size_t)gk * N + col0 + c4];
      *(float4*)&Bs[r][c4] = v;
    }
    __syncthreads();
    #pragma unroll
    for (int k = 0; k < BK; ++k) {
      float4 a0 = *(const float4*)&As[k][ty * 8];
      float4 a1 = *(const float4*)&As[k][ty * 8 + 4];
      float4 b0 = *(const float4*)&Bs[k][tx * 8];
      float4 b1 = *(const float4*)&Bs[k][tx * 8 + 4];
      float av[8] = {a0.x, a0.y, a0.z, a0.w, a1.x, a1.y, a1.z, a1.w};
      float bv[8] = {b0.x, b0.y, b0.z, b0.w, b1.x, b1.y, b1.z, b1.w};
      #pragma unroll
      for (int i = 0; i < 8; ++i)
        #pragma unroll
        for (int j = 0; j < 8; ++j)
          acc[i][j] = fmaf(av[i], bv[j], acc[i][j]);
    }
    __syncthreads();
  }
  #pragma unroll
  for (int i = 0; i < 8; ++i) {
    int gr = row0 + ty * 8 + i;
    if (gr >= M) continue;
    float s = scale[gr];
    #pragma unroll
    for (int j = 0; j < 8; j += 4) {
      float4 v = {acc[i][j] * s, acc[i][j + 1] * s, acc[i][j + 2] * s, acc[i][j + 3] * s};
      *(float4*)&C[(size_t)gr * N + col0 + tx * 8 + j] = v;
    }
  }
}

// ---------------------------------------------------------------- CSR gather, wave per node
template<int NF, bool RELU>
__global__ __launch_bounds__(256)
void gather_nodes(const int* __restrict__ off, const int* __restrict__ csr_src,
                  const float* __restrict__ h, const float* __restrict__ inv_d,
                  const float* __restrict__ bias, float* __restrict__ outbuf, int N)
{
  int node = blockIdx.x * 4 + (threadIdx.x >> 6);
  int lane = threadIdx.x & 63;
  if (node >= N) return;
  constexpr int NI = NF / 128;
  float2 acc[NI];
  #pragma unroll
  for (int i = 0; i < NI; ++i) acc[i] = {0.f, 0.f};

  int e0 = off[node], e1 = off[node + 1];
  for (int e = e0; e < e1; ++e) {
    const float* hr = h + (size_t)csr_src[e] * NF;
    #pragma unroll
    for (int i = 0; i < NI; ++i) {
      float2 v = *(const float2*)&hr[lane * 2 + i * 128];
      acc[i].x += v.x; acc[i].y += v.y;
    }
  }
  float s = inv_d[node];
  float* orow = outbuf + (size_t)node * NF;
  #pragma unroll
  for (int i = 0; i < NI; ++i) {
    int f = lane * 2 + i * 128;
    float2 v;
    v.x = fmaf(acc[i].x, s, bias[f]);
    v.y = fmaf(acc[i].y, s, bias[f + 1]);
    if (RELU) { v.x = fmaxf(v.x, 0.f); v.y = fmaxf(v.y, 0.f); }
    *(float2*)&orow[f] = v;
  }
}

// ---------------------------------------------------------------- CSR gather + classifier fused
__global__ __launch_bounds__(256)
void gather_classifier(const int* __restrict__ off, const int* __restrict__ csr_src,
                       const float* __restrict__ h, const float* __restrict__ inv_d,
                       const float* __restrict__ b2, const float* __restrict__ Wc,
                       const float* __restrict__ bc, float* __restrict__ out, int N)
{
  __shared__ float sWc[EMB * NCLS];
  for (int i = threadIdx.x; i < EMB * NCLS; i += 256) sWc[i] = Wc[i];
  __syncthreads();

  int node = blockIdx.x * 4 + (threadIdx.x >> 6);
  int lane = threadIdx.x & 63;
  if (node >= N) return;

  float2 acc[2] = {{0.f, 0.f}, {0.f, 0.f}};
  int e0 = off[node], e1 = off[node + 1];
  for (int e = e0; e < e1; ++e) {
    const float* hr = h + (size_t)csr_src[e] * EMB;
    #pragma unroll
    for (int i = 0; i < 2; ++i) {
      float2 v = *(const float2*)&hr[lane * 2 + i * 128];
      acc[i].x += v.x; acc[i].y += v.y;
    }
  }
  float s = inv_d[node];
  float c[NCLS];
  #pragma unroll
  for (int k = 0; k < NCLS; ++k) c[k] = 0.f;
  #pragma unroll
  for (int i = 0; i < 2; ++i) {
    int f = lane * 2 + i * 128;
    float hx = fmaf(acc[i].x, s, b2[f]);
    float hy = fmaf(acc[i].y, s, b2[f + 1]);
    #pragma unroll
    for (int k = 0; k < NCLS; ++k)
      c[k] += hx * sWc[f * NCLS + k] + hy * sWc[(f + 1) * NCLS + k];
  }
  #pragma unroll
  for (int k = 0; k < NCLS; ++k) {
    float v = c[k];
    #pragma unroll
    for (int o = 32; o > 0; o >>= 1) v += __shfl_down(v, o);
    if (lane == 0) out[(size_t)node * NCLS + k] = v + bc[k];
  }
}

// ---------------------------------------------------------------- launch
extern "C" void kernel_launch(void* const* d_in, const int* in_sizes, int n_in,
                              void* d_out, int out_size, void* d_ws, size_t ws_size,
                              hipStream_t stream) {
  const float* features = (const float*)d_in[0];
  const int*   esrc     = (const int*)d_in[1];
  const int*   edst     = (const int*)d_in[2];
  const float* W1       = (const float*)d_in[3];
  const float* b1       = (const float*)d_in[4];
  const float* W2       = (const float*)d_in[5];
  const float* b2       = (const float*)d_in[6];
  const float* Wc       = (const float*)d_in[7];
  const float* bc       = (const float*)d_in[8];
  float* out = (float*)d_out;

  // ---- workspace layout (re-derived every call; ws poisoned 0xAA)
  int* deg_out = (int*)d_ws;                    // 50000
  int* deg_in  = deg_out + NNODES;              // 50000
  int* cursor  = deg_in + NNODES;               // 50000
  int* row_off = cursor + NNODES;               // 50001
  int* csr_src = row_off + NNODES + 1;          // 400000
  float* inv_s = (float*)(csr_src + NEDGES);    // 50000
  float* inv_d = inv_s + NNODES;                // 50000
  ushort* bt_hi = (ushort*)(inv_d + NNODES);    // 384*1440 bf16
  ushort* bt_lo = bt_hi + (size_t)HID * KP1;    // 384*1440 bf16
  uintptr_t p16 = ((uintptr_t)(bt_lo + (size_t)HID * KP1) + 15) & ~(uintptr_t)15;
  float* bufA = (float*)p16;                    // [N, HID] (reused as [N, EMB])
  float* bufB = bufA + (size_t)NNODES * HID;    // [N, HID]

  // ---- graph prep
  hipMemsetAsync(deg_out, 0, 3 * NNODES * sizeof(int), stream);
  degree_kernel<<<1024, 256, 0, stream>>>(esrc, edst, deg_out, deg_in, NEDGES);
  inv_kernel<<<(NNODES + 255) / 256, 256, 0, stream>>>(deg_out, deg_in, inv_s, inv_d, NNODES);
  scan_kernel<<<1, 1024, 0, stream>>>(deg_in, row_off, NNODES);
  fill_csr<<<1024, 256, 0, stream>>>(esrc, edst, row_off, cursor, csr_src, NEDGES);

  // ---- layer 1 (split-bf16 MFMA): bufA = inv_s * (X@W1);  bufB = relu(inv_d*gather(bufA)+b1)
  split_transpose<<<dim3((KP1 + 255) / 256, HID), 256, 0, stream>>>(W1, bt_hi, bt_lo, INF, HID, KP1);
  gemm1_mfma<<<dim3(HID / 128, (NNODES + 127) / 128), 256, 0, stream>>>(
      features, bt_hi, bt_lo, bufA, inv_s, NNODES, HID, INF, KP1);
  gather_nodes<HID, true><<<(NNODES + 3) / 4, 256, 0, stream>>>(
      row_off, csr_src, bufA, inv_d, b1, bufB, NNODES);

  // ---- layer 2 + classifier
  gemm_scale<16><<<dim3(EMB / 128, (NNODES + 127) / 128), 256, 0, stream>>>(
      bufB, W2, bufA, inv_s, NNODES, EMB, HID);
  gather_classifier<<<(NNODES + 3) / 4, 256, 0, stream>>>(
      row_off, csr_src, bufA, inv_d, b2, Wc, bc, out, NNODES);
}

// Round 4
// 1222.305 us; speedup vs baseline: 1.1443x; 1.1443x over previous
//
#include <hip/hip_runtime.h>
#include <math.h>
#include <stdint.h>

constexpr int NNODES = 50000;
constexpr int NEDGES = 400000;
constexpr int INF = 1433;
constexpr int KP1 = 1440;          // INF padded to multiple of 32
constexpr int MP1 = 50048;         // NNODES padded to multiple of 128
constexpr int NRB = MP1 / 128;     // 391 row blocks
constexpr int NKT = KP1 / 32;      // 45 k-tiles
constexpr int HID = 384;
constexpr int EMB = 256;
constexpr int NCLS = 7;
constexpr int NWG1 = 3 * NRB;      // 1173 blocks for gemm1

typedef __attribute__((ext_vector_type(8))) short bf16x8_t;   // 8 bf16 in 4 VGPRs
typedef __attribute__((ext_vector_type(4))) float f32x4_t;    // MFMA accumulator

typedef __attribute__((address_space(3))) uint32_t lds_u32_t;
typedef const __attribute__((address_space(1))) uint32_t glb_u32_t;

// ---------------------------------------------------------------- degrees
__global__ void degree_kernel(const int* __restrict__ src, const int* __restrict__ dst,
                              int* __restrict__ dout, int* __restrict__ din, int E) {
  int i = blockIdx.x * blockDim.x + threadIdx.x;
  int stride = gridDim.x * blockDim.x;
  for (; i < E; i += stride) {
    atomicAdd(&dout[src[i]], 1);
    atomicAdd(&din[dst[i]], 1);
  }
}

__global__ void inv_kernel(const int* __restrict__ dout, const int* __restrict__ din,
                           float* __restrict__ inv_s, float* __restrict__ inv_d, int N) {
  int i = blockIdx.x * blockDim.x + threadIdx.x;
  if (i < N) {
    inv_s[i] = 1.0f / sqrtf(fmaxf((float)dout[i], 1.0f));
    inv_d[i] = 1.0f / sqrtf(fmaxf((float)din[i], 1.0f));
  }
}

// ---------------------------------------------------------------- exclusive scan (CSR offsets)
__global__ __launch_bounds__(1024)
void scan_kernel(const int* __restrict__ deg, int* __restrict__ off, int N) {
  __shared__ int buf[1024];
  __shared__ int carry;
  if (threadIdx.x == 0) carry = 0;
  __syncthreads();
  for (int base = 0; base < N; base += 1024) {
    int i = base + threadIdx.x;
    int v = (i < N) ? deg[i] : 0;
    buf[threadIdx.x] = v;
    __syncthreads();
    #pragma unroll
    for (int d = 1; d < 1024; d <<= 1) {
      int t = (threadIdx.x >= d) ? buf[threadIdx.x - d] : 0;
      __syncthreads();
      buf[threadIdx.x] += t;
      __syncthreads();
    }
    if (i < N) off[i] = carry + buf[threadIdx.x] - v;  // exclusive
    __syncthreads();
    if (threadIdx.x == 1023) carry += buf[1023];
    __syncthreads();
  }
  if (threadIdx.x == 0) off[N] = carry;
}

__global__ void fill_csr(const int* __restrict__ src, const int* __restrict__ dst,
                         const int* __restrict__ off, int* __restrict__ cursor,
                         int* __restrict__ csr_src, int E) {
  int i = blockIdx.x * blockDim.x + threadIdx.x;
  int stride = gridDim.x * blockDim.x;
  for (; i < E; i += stride) {
    int d = dst[i];
    int p = atomicAdd(&cursor[d], 1);
    csr_src[off[d] + p] = src[i];
  }
}

// ---------------------------------------------------------------- split helpers
__device__ __forceinline__ uint32_t split_pack(float v) {
  uint32_t u = __float_as_uint(v);
  float hiF = __uint_as_float(u & 0xFFFF0000u);
  uint32_t u2 = __float_as_uint(v - hiF);
  return (u2 & 0xFFFF0000u) | (u >> 16);        // lo<<16 | hi
}

// ---------------------------------------------------------------- A pre-pack: fp32 -> hi|lo dword, padded [MP1][KP1]
__global__ void convA(const float* __restrict__ A, uint32_t* __restrict__ Ap) {
  int kk = blockIdx.x * 256 + threadIdx.x;
  int r = blockIdx.y;
  if (kk >= KP1) return;
  float v = (r < NNODES && kk < INF) ? A[(size_t)r * INF + kk] : 0.f;
  Ap[(size_t)r * KP1 + kk] = split_pack(v);
}

// ---------------------------------------------------------------- W1 -> swizzled B tile images
// layout: [cb=3][T=45] tiles of 16KB; tile = hi-plane 8KB + lo-plane 8KB;
// within plane, (c,kk) at byte (c*64 + kk*2) ^ ((c&7)<<4)   (triangular-bit XOR -> bijective)
__global__ void convB(const float* __restrict__ W, char* __restrict__ Bp) {
  int T = blockIdx.x, cb = blockIdx.y;
  int kk = threadIdx.x & 31, c0 = threadIdx.x >> 5;
  char* tile = Bp + ((size_t)(cb * NKT) + T) * 16384;
  int gk = T * 32 + kk;
  #pragma unroll
  for (int i = 0; i < 16; ++i) {
    int c = c0 + i * 8;
    float v = (gk < INF) ? W[(size_t)gk * HID + cb * 128 + c] : 0.f;
    uint32_t p = split_pack(v);
    int bo = (c * 64 + kk * 2) ^ ((c & 7) << 4);
    *(ushort*)(tile + bo)        = (ushort)(p & 0xFFFFu);   // hi
    *(ushort*)(tile + 8192 + bo) = (ushort)(p >> 16);       // lo
  }
}

// ---------------------------------------------------------------- split-bf16 MFMA GEMM (layer 1), v2
// C[M,384] = (A@W1) * inv_s[row]; 3-term split (ah*bh + ah*bl + al*bh).
// 128x128 tile, 4 waves, global_load_lds staging (no reg staging -> no spill),
// pre-swizzled sources so LDS reads are XOR-swizzled & conflict-free.
__global__ __launch_bounds__(256, 2)
void gemm1_mfma2(const uint32_t* __restrict__ Ap, const char* __restrict__ Bp,
                 float* __restrict__ C, const float* __restrict__ scale)
{
  __shared__ __align__(16) char sA[16384];   // [128 r][32 kk] dwords, XOR ((r&7)<<4) on byte addr
  __shared__ __align__(16) char sB[16384];   // swizzled tile image (hi 8KB + lo 8KB)

  // bijective XCD chunk remap (m204): consecutive logical blocks (triples sharing
  // an A panel) land on the same XCD's L2.
  constexpr int q = NWG1 / 8, rr = NWG1 % 8;   // 146, 5
  int orig = blockIdx.x;
  int xcd = orig & 7, sub = orig >> 3;
  int logical = (xcd < rr ? xcd * (q + 1) : rr * (q + 1) + (xcd - rr) * q) + sub;
  int bx = logical % 3;        // col block (0..2)
  int by = logical / 3;        // row block (0..390)
  const int row0 = by * 128, col0 = bx * 128;

  const int tid = threadIdx.x;
  const int w = tid >> 6, l = tid & 63;
  const int wr = w >> 1, wc = w & 1;
  const int lane15 = l & 15, kg = l >> 4;

  // per-lane pre-swizzled A source offsets (bytes), rule-21 pattern:
  // LDS pos p holds logical (r = p>>7, kkbyte = (p&127) ^ ((r&7)<<4))
  size_t a_src[4];
  #pragma unroll
  for (int i = 0; i < 4; ++i) {
    int p = w * 4096 + i * 1024 + l * 16;
    int r = p >> 7;
    int kb = (p & 127) ^ ((r & 7) << 4);
    a_src[i] = ((size_t)(row0 + r) * KP1) * 4 + kb;
  }
  const char* Ab = (const char*)Ap;
  const char* Btile = Bp + (size_t)(bx * NKT) * 16384;

  f32x4_t acc[4][4];
  #pragma unroll
  for (int mi = 0; mi < 4; ++mi)
    #pragma unroll
    for (int ni = 0; ni < 4; ++ni) acc[mi][ni] = {0.f, 0.f, 0.f, 0.f};

  for (int T = 0; T < NKT; ++T) {
    // ---- stage tiles: pure async copies, zero registers held
    #pragma unroll
    for (int i = 0; i < 4; ++i) {
      __builtin_amdgcn_global_load_lds(
          (glb_u32_t*)(Ab + a_src[i] + (size_t)T * 128),
          (lds_u32_t*)(sA + w * 4096 + i * 1024), 16, 0, 0);
    }
    #pragma unroll
    for (int i = 0; i < 4; ++i) {
      int p = w * 4096 + i * 1024;
      __builtin_amdgcn_global_load_lds(
          (glb_u32_t*)(Btile + (size_t)T * 16384 + p + l * 16),
          (lds_u32_t*)(sB + p), 16, 0, 0);
    }
    __syncthreads();   // drains vmcnt -> tiles visible

    // ---- B fragments (hi/lo planes, swizzled read)
    bf16x8_t bh[4], bl[4];
    #pragma unroll
    for (int ni = 0; ni < 4; ++ni) {
      int c = wc * 64 + ni * 16 + lane15;
      int bo = (c * 64 + kg * 16) ^ ((c & 7) << 4);
      bh[ni] = *(const bf16x8_t*)(sB + bo);
      bl[ni] = *(const bf16x8_t*)(sB + 8192 + bo);
    }
    // ---- A fragments per mi (short live ranges), unzip hi/lo, 3-term MFMA
    #pragma unroll
    for (int mi = 0; mi < 4; ++mi) {
      int ra = wr * 64 + mi * 16 + lane15;
      int a0 = (ra * 128 + kg * 32) ^ ((ra & 7) << 4);
      uint4 d0 = *(const uint4*)(sA + a0);
      uint4 d1 = *(const uint4*)(sA + (a0 ^ 16));
      union { uint32_t u[4]; bf16x8_t v; } th, tl;
      th.u[0] = (d0.x & 0xFFFFu) | (d0.y << 16);
      th.u[1] = (d0.z & 0xFFFFu) | (d0.w << 16);
      th.u[2] = (d1.x & 0xFFFFu) | (d1.y << 16);
      th.u[3] = (d1.z & 0xFFFFu) | (d1.w << 16);
      tl.u[0] = (d0.x >> 16) | (d0.y & 0xFFFF0000u);
      tl.u[1] = (d0.z >> 16) | (d0.w & 0xFFFF0000u);
      tl.u[2] = (d1.x >> 16) | (d1.y & 0xFFFF0000u);
      tl.u[3] = (d1.z >> 16) | (d1.w & 0xFFFF0000u);
      #pragma unroll
      for (int ni = 0; ni < 4; ++ni) {
        acc[mi][ni] = __builtin_amdgcn_mfma_f32_16x16x32_bf16(th.v, bh[ni], acc[mi][ni], 0, 0, 0);
        acc[mi][ni] = __builtin_amdgcn_mfma_f32_16x16x32_bf16(th.v, bl[ni], acc[mi][ni], 0, 0, 0);
        acc[mi][ni] = __builtin_amdgcn_mfma_f32_16x16x32_bf16(tl.v, bh[ni], acc[mi][ni], 0, 0, 0);
      }
    }
    __syncthreads();   // all reads done before next tile overwrites
  }

  // ---- epilogue (verbatim from verified v3): D row=(l>>4)*4+j, col=l&15
  #pragma unroll
  for (int mi = 0; mi < 4; ++mi) {
    #pragma unroll
    for (int j = 0; j < 4; ++j) {
      int gr = row0 + wr * 64 + mi * 16 + kg * 4 + j;
      if (gr >= NNODES) continue;
      float s = scale[gr];
      #pragma unroll
      for (int ni = 0; ni < 4; ++ni) {
        int gc = col0 + wc * 64 + ni * 16 + lane15;
        C[(size_t)gr * HID + gc] = acc[mi][ni][j] * s;
      }
    }
  }
}

// ---------------------------------------------------------------- fp32 GEMM (layer 2 + fallback)
template<int BK>
__global__ __launch_bounds__(256)
void gemm_scale(const float* __restrict__ A, const float* __restrict__ B,
                float* __restrict__ C, const float* __restrict__ scale,
                int M, int N, int K)
{
  constexpr int BM = 128, BN = 128;
  constexpr int LDA = BM + 4;
  constexpr int LDB = BN + 4;
  __shared__ float As[BK][LDA];
  __shared__ float Bs[BK][LDB];

  const int tid = threadIdx.x;
  const int tx = tid & 15;
  const int ty = tid >> 4;
  const int row0 = blockIdx.y * BM;
  const int col0 = blockIdx.x * BN;

  float acc[8][8];
  #pragma unroll
  for (int i = 0; i < 8; ++i)
    #pragma unroll
    for (int j = 0; j < 8; ++j) acc[i][j] = 0.f;

  for (int kt = 0; kt < K; kt += BK) {
    #pragma unroll
    for (int p = 0; p < BM / 16; ++p) {
      int r = (tid >> 4) + p * 16;
      int k = tid & 15;
      int gr = row0 + r, gk = kt + k;
      float v = 0.f;
      if (gr < M && gk < K) v = A[(size_t)gr * K + gk];
      As[k][r] = v;
    }
    #pragma unroll
    for (int p = 0; p < BK / 8; ++p) {
      int r = (tid >> 5) + p * 8;
      int c4 = (tid & 31) * 4;
      int gk = kt + r;
      float4 v = {0.f, 0.f, 0.f, 0.f};
      if (gk < K) v = *(const float4*)&B[(size_t)gk * N + col0 + c4];
      *(float4*)&Bs[r][c4] = v;
    }
    __syncthreads();
    #pragma unroll
    for (int k = 0; k < BK; ++k) {
      float4 a0 = *(const float4*)&As[k][ty * 8];
      float4 a1 = *(const float4*)&As[k][ty * 8 + 4];
      float4 b0 = *(const float4*)&Bs[k][tx * 8];
      float4 b1 = *(const float4*)&Bs[k][tx * 8 + 4];
      float av[8] = {a0.x, a0.y, a0.z, a0.w, a1.x, a1.y, a1.z, a1.w};
      float bv[8] = {b0.x, b0.y, b0.z, b0.w, b1.x, b1.y, b1.z, b1.w};
      #pragma unroll
      for (int i = 0; i < 8; ++i)
        #pragma unroll
        for (int j = 0; j < 8; ++j)
          acc[i][j] = fmaf(av[i], bv[j], acc[i][j]);
    }
    __syncthreads();
  }
  #pragma unroll
  for (int i = 0; i < 8; ++i) {
    int gr = row0 + ty * 8 + i;
    if (gr >= M) continue;
    float s = scale[gr];
    #pragma unroll
    for (int j = 0; j < 8; j += 4) {
      float4 v = {acc[i][j] * s, acc[i][j + 1] * s, acc[i][j + 2] * s, acc[i][j + 3] * s};
      *(float4*)&C[(size_t)gr * N + col0 + tx * 8 + j] = v;
    }
  }
}

// ---------------------------------------------------------------- CSR gather, wave per node
template<int NF, bool RELU>
__global__ __launch_bounds__(256)
void gather_nodes(const int* __restrict__ off, const int* __restrict__ csr_src,
                  const float* __restrict__ h, const float* __restrict__ inv_d,
                  const float* __restrict__ bias, float* __restrict__ outbuf, int N)
{
  int node = blockIdx.x * 4 + (threadIdx.x >> 6);
  int lane = threadIdx.x & 63;
  if (node >= N) return;
  constexpr int NI = NF / 128;
  float2 acc[NI];
  #pragma unroll
  for (int i = 0; i < NI; ++i) acc[i] = {0.f, 0.f};

  int e0 = off[node], e1 = off[node + 1];
  for (int e = e0; e < e1; ++e) {
    const float* hr = h + (size_t)csr_src[e] * NF;
    #pragma unroll
    for (int i = 0; i < NI; ++i) {
      float2 v = *(const float2*)&hr[lane * 2 + i * 128];
      acc[i].x += v.x; acc[i].y += v.y;
    }
  }
  float s = inv_d[node];
  float* orow = outbuf + (size_t)node * NF;
  #pragma unroll
  for (int i = 0; i < NI; ++i) {
    int f = lane * 2 + i * 128;
    float2 v;
    v.x = fmaf(acc[i].x, s, bias[f]);
    v.y = fmaf(acc[i].y, s, bias[f + 1]);
    if (RELU) { v.x = fmaxf(v.x, 0.f); v.y = fmaxf(v.y, 0.f); }
    *(float2*)&orow[f] = v;
  }
}

// ---------------------------------------------------------------- CSR gather + classifier fused
__global__ __launch_bounds__(256)
void gather_classifier(const int* __restrict__ off, const int* __restrict__ csr_src,
                       const float* __restrict__ h, const float* __restrict__ inv_d,
                       const float* __restrict__ b2, const float* __restrict__ Wc,
                       const float* __restrict__ bc, float* __restrict__ out, int N)
{
  __shared__ float sWc[EMB * NCLS];
  for (int i = threadIdx.x; i < EMB * NCLS; i += 256) sWc[i] = Wc[i];
  __syncthreads();

  int node = blockIdx.x * 4 + (threadIdx.x >> 6);
  int lane = threadIdx.x & 63;
  if (node >= N) return;

  float2 acc[2] = {{0.f, 0.f}, {0.f, 0.f}};
  int e0 = off[node], e1 = off[node + 1];
  for (int e = e0; e < e1; ++e) {
    const float* hr = h + (size_t)csr_src[e] * EMB;
    #pragma unroll
    for (int i = 0; i < 2; ++i) {
      float2 v = *(const float2*)&hr[lane * 2 + i * 128];
      acc[i].x += v.x; acc[i].y += v.y;
    }
  }
  float s = inv_d[node];
  float c[NCLS];
  #pragma unroll
  for (int k = 0; k < NCLS; ++k) c[k] = 0.f;
  #pragma unroll
  for (int i = 0; i < 2; ++i) {
    int f = lane * 2 + i * 128;
    float hx = fmaf(acc[i].x, s, b2[f]);
    float hy = fmaf(acc[i].y, s, b2[f + 1]);
    #pragma unroll
    for (int k = 0; k < NCLS; ++k)
      c[k] += hx * sWc[f * NCLS + k] + hy * sWc[(f + 1) * NCLS + k];
  }
  #pragma unroll
  for (int k = 0; k < NCLS; ++k) {
    float v = c[k];
    #pragma unroll
    for (int o = 32; o > 0; o >>= 1) v += __shfl_down(v, o);
    if (lane == 0) out[(size_t)node * NCLS + k] = v + bc[k];
  }
}

// ---------------------------------------------------------------- launch
extern "C" void kernel_launch(void* const* d_in, const int* in_sizes, int n_in,
                              void* d_out, int out_size, void* d_ws, size_t ws_size,
                              hipStream_t stream) {
  const float* features = (const float*)d_in[0];
  const int*   esrc     = (const int*)d_in[1];
  const int*   edst     = (const int*)d_in[2];
  const float* W1       = (const float*)d_in[3];
  const float* b1       = (const float*)d_in[4];
  const float* W2       = (const float*)d_in[5];
  const float* b2       = (const float*)d_in[6];
  const float* Wc       = (const float*)d_in[7];
  const float* bc       = (const float*)d_in[8];
  float* out = (float*)d_out;

  // ---- workspace layout (re-derived every call; ws poisoned 0xAA)
  int* deg_out = (int*)d_ws;                    // 50000
  int* deg_in  = deg_out + NNODES;              // 50000
  int* cursor  = deg_in + NNODES;               // 50000
  int* row_off = cursor + NNODES;               // 50001
  int* csr_src = row_off + NNODES + 1;          // 400000
  float* inv_s = (float*)(csr_src + NEDGES);    // 50000
  float* inv_d = inv_s + NNODES;                // 50000
  uintptr_t p16 = ((uintptr_t)(inv_d + NNODES) + 15) & ~(uintptr_t)15;
  float* bufA = (float*)p16;                    // [N, HID] (reused as [N, EMB])
  float* bufB = bufA + (size_t)NNODES * HID;    // [N, HID]
  char*  Bp   = (char*)(bufB + (size_t)NNODES * HID);          // 3*45*16KB swizzled tiles
  uint32_t* Ap = (uint32_t*)(Bp + (size_t)3 * NKT * 16384);    // [MP1][KP1] packed dwords

  size_t required = (uintptr_t)(Ap + (size_t)MP1 * KP1) - (uintptr_t)d_ws;
  bool use_mfma = ws_size >= required;

  // ---- graph prep
  hipMemsetAsync(deg_out, 0, 3 * NNODES * sizeof(int), stream);
  degree_kernel<<<1024, 256, 0, stream>>>(esrc, edst, deg_out, deg_in, NEDGES);
  inv_kernel<<<(NNODES + 255) / 256, 256, 0, stream>>>(deg_out, deg_in, inv_s, inv_d, NNODES);
  scan_kernel<<<1, 1024, 0, stream>>>(deg_in, row_off, NNODES);
  fill_csr<<<1024, 256, 0, stream>>>(esrc, edst, row_off, cursor, csr_src, NEDGES);

  // ---- layer 1: bufA = inv_s * (X@W1)
  if (use_mfma) {
    convA<<<dim3((KP1 + 255) / 256, MP1), 256, 0, stream>>>(features, Ap);
    convB<<<dim3(NKT, 3), 256, 0, stream>>>(W1, Bp);
    gemm1_mfma2<<<NWG1, 256, 0, stream>>>(Ap, Bp, bufA, inv_s);
  } else {
    gemm_scale<16><<<dim3(HID / 128, (NNODES + 127) / 128), 256, 0, stream>>>(
        features, W1, bufA, inv_s, NNODES, HID, INF);
  }
  // bufB = relu(inv_d * gather(bufA) + b1)
  gather_nodes<HID, true><<<(NNODES + 3) / 4, 256, 0, stream>>>(
      row_off, csr_src, bufA, inv_d, b1, bufB, NNODES);

  // ---- layer 2 + classifier
  gemm_scale<16><<<dim3(EMB / 128, (NNODES + 127) / 128), 256, 0, stream>>>(
      bufB, W2, bufA, inv_s, NNODES, EMB, HID);
  gather_classifier<<<(NNODES + 3) / 4, 256, 0, stream>>>(
      row_off, csr_src, bufA, inv_d, b2, Wc, bc, out, NNODES);
}

// Round 5
// 1035.961 us; speedup vs baseline: 1.3501x; 1.1799x over previous
//
#include <hip/hip_runtime.h>
#include <math.h>
#include <stdint.h>

constexpr int NNODES = 50000;
constexpr int NEDGES = 400000;
constexpr int INF = 1433;
constexpr int KP1 = 1440;          // INF padded to multiple of 32
constexpr int MP1 = 50048;         // NNODES padded to multiple of 128
constexpr int NRB = MP1 / 128;     // 391 row blocks
constexpr int NKT1 = KP1 / 32;     // 45 k-tiles (layer 1)
constexpr int HID = 384;
constexpr int NKT2 = HID / 32;     // 12 k-tiles (layer 2)
constexpr int EMB = 256;
constexpr int NCLS = 7;

typedef __attribute__((ext_vector_type(8))) short bf16x8_t;   // 8 bf16 in 4 VGPRs
typedef __attribute__((ext_vector_type(4))) float f32x4_t;    // MFMA accumulator

typedef __attribute__((address_space(3))) uint32_t lds_u32_t;
typedef const __attribute__((address_space(1))) uint32_t glb_u32_t;

// ---------------------------------------------------------------- degrees
__global__ void degree_kernel(const int* __restrict__ src, const int* __restrict__ dst,
                              int* __restrict__ dout, int* __restrict__ din, int E) {
  int i = blockIdx.x * blockDim.x + threadIdx.x;
  int stride = gridDim.x * blockDim.x;
  for (; i < E; i += stride) {
    atomicAdd(&dout[src[i]], 1);
    atomicAdd(&din[dst[i]], 1);
  }
}

__global__ void inv_kernel(const int* __restrict__ dout, const int* __restrict__ din,
                           float* __restrict__ inv_s, float* __restrict__ inv_d, int N) {
  int i = blockIdx.x * blockDim.x + threadIdx.x;
  if (i < N) {
    inv_s[i] = 1.0f / sqrtf(fmaxf((float)dout[i], 1.0f));
    inv_d[i] = 1.0f / sqrtf(fmaxf((float)din[i], 1.0f));
  }
}

// ---------------------------------------------------------------- exclusive scan (CSR offsets)
__global__ __launch_bounds__(1024)
void scan_kernel(const int* __restrict__ deg, int* __restrict__ off, int N) {
  __shared__ int buf[1024];
  __shared__ int carry;
  if (threadIdx.x == 0) carry = 0;
  __syncthreads();
  for (int base = 0; base < N; base += 1024) {
    int i = base + threadIdx.x;
    int v = (i < N) ? deg[i] : 0;
    buf[threadIdx.x] = v;
    __syncthreads();
    #pragma unroll
    for (int d = 1; d < 1024; d <<= 1) {
      int t = (threadIdx.x >= d) ? buf[threadIdx.x - d] : 0;
      __syncthreads();
      buf[threadIdx.x] += t;
      __syncthreads();
    }
    if (i < N) off[i] = carry + buf[threadIdx.x] - v;  // exclusive
    __syncthreads();
    if (threadIdx.x == 1023) carry += buf[1023];
    __syncthreads();
  }
  if (threadIdx.x == 0) off[N] = carry;
}

__global__ void fill_csr(const int* __restrict__ src, const int* __restrict__ dst,
                         const int* __restrict__ off, int* __restrict__ cursor,
                         int* __restrict__ csr_src, int E) {
  int i = blockIdx.x * blockDim.x + threadIdx.x;
  int stride = gridDim.x * blockDim.x;
  for (; i < E; i += stride) {
    int d = dst[i];
    int p = atomicAdd(&cursor[d], 1);
    csr_src[off[d] + p] = src[i];
  }
}

// ---------------------------------------------------------------- split helpers
__device__ __forceinline__ uint32_t split_pack(float v) {
  uint32_t u = __float_as_uint(v);
  float hiF = __uint_as_float(u & 0xFFFF0000u);
  uint32_t u2 = __float_as_uint(v - hiF);
  return (u2 & 0xFFFF0000u) | (u >> 16);        // lo<<16 | hi
}

// ---------------------------------------------------------------- A pre-pack: fp32 -> hi|lo dword, [MP1][KP1]
// 4 dwords per thread (4 loads in flight, one uint4 store)
__global__ void convA(const float* __restrict__ A, uint32_t* __restrict__ Ap) {
  int k4 = blockIdx.x * 256 + threadIdx.x;
  int r = blockIdx.y;
  if (k4 >= KP1 / 4) return;
  int k = k4 * 4;
  uint4 o = {0, 0, 0, 0};
  if (r < NNODES) {
    const float* row = A + (size_t)r * INF;
    if (k + 3 < INF) {
      float a0 = row[k], a1 = row[k + 1], a2 = row[k + 2], a3 = row[k + 3];
      o.x = split_pack(a0); o.y = split_pack(a1); o.z = split_pack(a2); o.w = split_pack(a3);
    } else {
      if (k + 0 < INF) o.x = split_pack(row[k + 0]);
      if (k + 1 < INF) o.y = split_pack(row[k + 1]);
      if (k + 2 < INF) o.z = split_pack(row[k + 2]);
      if (k + 3 < INF) o.w = split_pack(row[k + 3]);
    }
  }
  *(uint4*)&Ap[(size_t)r * KP1 + k] = o;   // row stride 5760B: 16B-aligned
}

// ---------------------------------------------------------------- W -> swizzled B tile images
// layout: [cb][T] tiles of 16KB; tile = hi-plane 8KB + lo-plane 8KB;
// within plane, (c,kk) at byte (c*64 + kk*2) ^ ((c&7)<<4)   (verified R4)
template<int KDIM, int NDIM, int NKTILES>
__global__ void convB(const float* __restrict__ W, char* __restrict__ Bp) {
  int T = blockIdx.x, cb = blockIdx.y;
  int kk = threadIdx.x & 31, c0 = threadIdx.x >> 5;
  char* tile = Bp + ((size_t)cb * NKTILES + T) * 16384;
  int gk = T * 32 + kk;
  #pragma unroll
  for (int i = 0; i < 16; ++i) {
    int c = c0 + i * 8;
    float v = (gk < KDIM) ? W[(size_t)gk * NDIM + cb * 128 + c] : 0.f;
    uint32_t p = split_pack(v);
    int bo = (c * 64 + kk * 2) ^ ((c & 7) << 4);
    *(ushort*)(tile + bo)        = (ushort)(p & 0xFFFFu);   // hi
    *(ushort*)(tile + 8192 + bo) = (ushort)(p >> 16);       // lo
  }
}

// ---------------------------------------------------------------- split-bf16 MFMA GEMM (verified R4, templatized)
// C[M,NOUT] = (A@B) * scale[row]; 3-term split (ah*bh + ah*bl + al*bh).
// 128x128 tile, 4 waves, global_load_lds staging, pre-swizzled sources.
// KPD = packed-A row stride (dwords); NCOLB = NOUT/128; NKTILES = K/32.
template<int KPD, int NOUT, int NCOLB, int NKTILES>
__global__ __launch_bounds__(256, 2)
void gemm_mfma(const uint32_t* __restrict__ Ap, const char* __restrict__ Bp,
               float* __restrict__ C, const float* __restrict__ scale)
{
  __shared__ __align__(16) char sA[16384];   // [128 r][32 kk] dwords, XOR ((r&7)<<4) on byte addr
  __shared__ __align__(16) char sB[16384];   // swizzled tile image (hi 8KB + lo 8KB)

  // bijective XCD chunk remap (m204)
  constexpr int NWG = NCOLB * NRB;
  constexpr int q = NWG / 8, rr = NWG % 8;
  int orig = blockIdx.x;
  int xcd = orig & 7, sub = orig >> 3;
  int logical = (xcd < rr ? xcd * (q + 1) : rr * (q + 1) + (xcd - rr) * q) + sub;
  int bx = logical % NCOLB;
  int by = logical / NCOLB;
  const int row0 = by * 128, col0 = bx * 128;

  const int tid = threadIdx.x;
  const int w = tid >> 6, l = tid & 63;
  const int wr = w >> 1, wc = w & 1;
  const int lane15 = l & 15, kg = l >> 4;

  // per-lane pre-swizzled A source offsets (rule-21: linear LDS dest + inv-swz source)
  size_t a_src[4];
  #pragma unroll
  for (int i = 0; i < 4; ++i) {
    int p = w * 4096 + i * 1024 + l * 16;
    int r = p >> 7;
    int kb = (p & 127) ^ ((r & 7) << 4);
    a_src[i] = ((size_t)(row0 + r) * KPD) * 4 + kb;
  }
  const char* Ab = (const char*)Ap;
  const char* Btile = Bp + (size_t)(bx * NKTILES) * 16384;

  f32x4_t acc[4][4];
  #pragma unroll
  for (int mi = 0; mi < 4; ++mi)
    #pragma unroll
    for (int ni = 0; ni < 4; ++ni) acc[mi][ni] = {0.f, 0.f, 0.f, 0.f};

  for (int T = 0; T < NKTILES; ++T) {
    // ---- stage tiles: pure async copies, zero registers held
    #pragma unroll
    for (int i = 0; i < 4; ++i) {
      __builtin_amdgcn_global_load_lds(
          (glb_u32_t*)(Ab + a_src[i] + (size_t)T * 128),
          (lds_u32_t*)(sA + w * 4096 + i * 1024), 16, 0, 0);
    }
    #pragma unroll
    for (int i = 0; i < 4; ++i) {
      int p = w * 4096 + i * 1024;
      __builtin_amdgcn_global_load_lds(
          (glb_u32_t*)(Btile + (size_t)T * 16384 + p + l * 16),
          (lds_u32_t*)(sB + p), 16, 0, 0);
    }
    __syncthreads();   // drains vmcnt -> tiles visible

    // ---- B fragments (hi/lo planes, swizzled read)
    bf16x8_t bh[4], bl[4];
    #pragma unroll
    for (int ni = 0; ni < 4; ++ni) {
      int c = wc * 64 + ni * 16 + lane15;
      int bo = (c * 64 + kg * 16) ^ ((c & 7) << 4);
      bh[ni] = *(const bf16x8_t*)(sB + bo);
      bl[ni] = *(const bf16x8_t*)(sB + 8192 + bo);
    }
    // ---- A fragments per mi, unzip hi/lo, 3-term MFMA
    #pragma unroll
    for (int mi = 0; mi < 4; ++mi) {
      int ra = wr * 64 + mi * 16 + lane15;
      int a0 = (ra * 128 + kg * 32) ^ ((ra & 7) << 4);
      uint4 d0 = *(const uint4*)(sA + a0);
      uint4 d1 = *(const uint4*)(sA + (a0 ^ 16));
      union { uint32_t u[4]; bf16x8_t v; } th, tl;
      th.u[0] = (d0.x & 0xFFFFu) | (d0.y << 16);
      th.u[1] = (d0.z & 0xFFFFu) | (d0.w << 16);
      th.u[2] = (d1.x & 0xFFFFu) | (d1.y << 16);
      th.u[3] = (d1.z & 0xFFFFu) | (d1.w << 16);
      tl.u[0] = (d0.x >> 16) | (d0.y & 0xFFFF0000u);
      tl.u[1] = (d0.z >> 16) | (d0.w & 0xFFFF0000u);
      tl.u[2] = (d1.x >> 16) | (d1.y & 0xFFFF0000u);
      tl.u[3] = (d1.z >> 16) | (d1.w & 0xFFFF0000u);
      #pragma unroll
      for (int ni = 0; ni < 4; ++ni) {
        acc[mi][ni] = __builtin_amdgcn_mfma_f32_16x16x32_bf16(th.v, bh[ni], acc[mi][ni], 0, 0, 0);
        acc[mi][ni] = __builtin_amdgcn_mfma_f32_16x16x32_bf16(th.v, bl[ni], acc[mi][ni], 0, 0, 0);
        acc[mi][ni] = __builtin_amdgcn_mfma_f32_16x16x32_bf16(tl.v, bh[ni], acc[mi][ni], 0, 0, 0);
      }
    }
    __syncthreads();   // all reads done before next tile overwrites
  }

  // ---- epilogue: D row=(l>>4)*4+j, col=l&15 (verified); scale rows
  #pragma unroll
  for (int mi = 0; mi < 4; ++mi) {
    #pragma unroll
    for (int j = 0; j < 4; ++j) {
      int gr = row0 + wr * 64 + mi * 16 + kg * 4 + j;
      if (gr >= NNODES) continue;
      float s = scale[gr];
      #pragma unroll
      for (int ni = 0; ni < 4; ++ni) {
        int gc = col0 + wc * 64 + ni * 16 + lane15;
        C[(size_t)gr * NOUT + gc] = acc[mi][ni][j] * s;
      }
    }
  }
}

// ---------------------------------------------------------------- fp32 GEMM (fallback only)
template<int BK>
__global__ __launch_bounds__(256)
void gemm_scale(const float* __restrict__ A, const float* __restrict__ B,
                float* __restrict__ C, const float* __restrict__ scale,
                int M, int N, int K)
{
  constexpr int BM = 128, BN = 128;
  constexpr int LDA = BM + 4;
  constexpr int LDB = BN + 4;
  __shared__ float As[BK][LDA];
  __shared__ float Bs[BK][LDB];

  const int tid = threadIdx.x;
  const int tx = tid & 15;
  const int ty = tid >> 4;
  const int row0 = blockIdx.y * BM;
  const int col0 = blockIdx.x * BN;

  float acc[8][8];
  #pragma unroll
  for (int i = 0; i < 8; ++i)
    #pragma unroll
    for (int j = 0; j < 8; ++j) acc[i][j] = 0.f;

  for (int kt = 0; kt < K; kt += BK) {
    #pragma unroll
    for (int p = 0; p < BM / 16; ++p) {
      int r = (tid >> 4) + p * 16;
      int k = tid & 15;
      int gr = row0 + r, gk = kt + k;
      float v = 0.f;
      if (gr < M && gk < K) v = A[(size_t)gr * K + gk];
      As[k][r] = v;
    }
    #pragma unroll
    for (int p = 0; p < BK / 8; ++p) {
      int r = (tid >> 5) + p * 8;
      int c4 = (tid & 31) * 4;
      int gk = kt + r;
      float4 v = {0.f, 0.f, 0.f, 0.f};
      if (gk < K) v = *(const float4*)&B[(size_t)gk * N + col0 + c4];
      *(float4*)&Bs[r][c4] = v;
    }
    __syncthreads();
    #pragma unroll
    for (int k = 0; k < BK; ++k) {
      float4 a0 = *(const float4*)&As[k][ty * 8];
      float4 a1 = *(const float4*)&As[k][ty * 8 + 4];
      float4 b0 = *(const float4*)&Bs[k][tx * 8];
      float4 b1 = *(const float4*)&Bs[k][tx * 8 + 4];
      float av[8] = {a0.x, a0.y, a0.z, a0.w, a1.x, a1.y, a1.z, a1.w};
      float bv[8] = {b0.x, b0.y, b0.z, b0.w, b1.x, b1.y, b1.z, b1.w};
      #pragma unroll
      for (int i = 0; i < 8; ++i)
        #pragma unroll
        for (int j = 0; j < 8; ++j)
          acc[i][j] = fmaf(av[i], bv[j], acc[i][j]);
    }
    __syncthreads();
  }
  #pragma unroll
  for (int i = 0; i < 8; ++i) {
    int gr = row0 + ty * 8 + i;
    if (gr >= M) continue;
    float s = scale[gr];
    #pragma unroll
    for (int j = 0; j < 8; j += 4) {
      float4 v = {acc[i][j] * s, acc[i][j + 1] * s, acc[i][j + 2] * s, acc[i][j + 3] * s};
      *(float4*)&C[(size_t)gr * N + col0 + tx * 8 + j] = v;
    }
  }
}

// ---------------------------------------------------------------- CSR gather, wave per node (fp32 out; fallback)
template<int NF, bool RELU>
__global__ __launch_bounds__(256)
void gather_nodes(const int* __restrict__ off, const int* __restrict__ csr_src,
                  const float* __restrict__ h, const float* __restrict__ inv_d,
                  const float* __restrict__ bias, float* __restrict__ outbuf, int N)
{
  int node = blockIdx.x * 4 + (threadIdx.x >> 6);
  int lane = threadIdx.x & 63;
  if (node >= N) return;
  constexpr int NI = NF / 128;
  float2 acc[NI];
  #pragma unroll
  for (int i = 0; i < NI; ++i) acc[i] = {0.f, 0.f};

  int e0 = off[node], e1 = off[node + 1];
  for (int e = e0; e < e1; ++e) {
    const float* hr = h + (size_t)csr_src[e] * NF;
    #pragma unroll
    for (int i = 0; i < NI; ++i) {
      float2 v = *(const float2*)&hr[lane * 2 + i * 128];
      acc[i].x += v.x; acc[i].y += v.y;
    }
  }
  float s = inv_d[node];
  float* orow = outbuf + (size_t)node * NF;
  #pragma unroll
  for (int i = 0; i < NI; ++i) {
    int f = lane * 2 + i * 128;
    float2 v;
    v.x = fmaf(acc[i].x, s, bias[f]);
    v.y = fmaf(acc[i].y, s, bias[f + 1]);
    if (RELU) { v.x = fmaxf(v.x, 0.f); v.y = fmaxf(v.y, 0.f); }
    *(float2*)&orow[f] = v;
  }
}

// ---------------------------------------------------------------- CSR gather -> relu -> PACKED hi|lo output
// emits layer-2's A matrix directly in gemm_mfma's packed format (free conversion)
__global__ __launch_bounds__(256)
void gather_pack(const int* __restrict__ off, const int* __restrict__ csr_src,
                 const float* __restrict__ h, const float* __restrict__ inv_d,
                 const float* __restrict__ bias, uint32_t* __restrict__ outp, int N)
{
  int node = blockIdx.x * 4 + (threadIdx.x >> 6);
  int lane = threadIdx.x & 63;
  if (node >= N) return;
  float2 acc[3];
  #pragma unroll
  for (int i = 0; i < 3; ++i) acc[i] = {0.f, 0.f};

  int e0 = off[node], e1 = off[node + 1];
  for (int e = e0; e < e1; ++e) {
    const float* hr = h + (size_t)csr_src[e] * HID;
    #pragma unroll
    for (int i = 0; i < 3; ++i) {
      float2 v = *(const float2*)&hr[lane * 2 + i * 128];
      acc[i].x += v.x; acc[i].y += v.y;
    }
  }
  float s = inv_d[node];
  uint32_t* orow = outp + (size_t)node * HID;
  #pragma unroll
  for (int i = 0; i < 3; ++i) {
    int f = lane * 2 + i * 128;
    float vx = fmaxf(fmaf(acc[i].x, s, bias[f]), 0.f);
    float vy = fmaxf(fmaf(acc[i].y, s, bias[f + 1]), 0.f);
    uint2 o = {split_pack(vx), split_pack(vy)};
    *(uint2*)&orow[f] = o;
  }
}

// ---------------------------------------------------------------- CSR gather + classifier fused
__global__ __launch_bounds__(256)
void gather_classifier(const int* __restrict__ off, const int* __restrict__ csr_src,
                       const float* __restrict__ h, const float* __restrict__ inv_d,
                       const float* __restrict__ b2, const float* __restrict__ Wc,
                       const float* __restrict__ bc, float* __restrict__ out, int N)
{
  __shared__ float sWc[EMB * NCLS];
  for (int i = threadIdx.x; i < EMB * NCLS; i += 256) sWc[i] = Wc[i];
  __syncthreads();

  int node = blockIdx.x * 4 + (threadIdx.x >> 6);
  int lane = threadIdx.x & 63;
  if (node >= N) return;

  float2 acc[2] = {{0.f, 0.f}, {0.f, 0.f}};
  int e0 = off[node], e1 = off[node + 1];
  for (int e = e0; e < e1; ++e) {
    const float* hr = h + (size_t)csr_src[e] * EMB;
    #pragma unroll
    for (int i = 0; i < 2; ++i) {
      float2 v = *(const float2*)&hr[lane * 2 + i * 128];
      acc[i].x += v.x; acc[i].y += v.y;
    }
  }
  float s = inv_d[node];
  float c[NCLS];
  #pragma unroll
  for (int k = 0; k < NCLS; ++k) c[k] = 0.f;
  #pragma unroll
  for (int i = 0; i < 2; ++i) {
    int f = lane * 2 + i * 128;
    float hx = fmaf(acc[i].x, s, b2[f]);
    float hy = fmaf(acc[i].y, s, b2[f + 1]);
    #pragma unroll
    for (int k = 0; k < NCLS; ++k)
      c[k] += hx * sWc[f * NCLS + k] + hy * sWc[(f + 1) * NCLS + k];
  }
  #pragma unroll
  for (int k = 0; k < NCLS; ++k) {
    float v = c[k];
    #pragma unroll
    for (int o = 32; o > 0; o >>= 1) v += __shfl_down(v, o);
    if (lane == 0) out[(size_t)node * NCLS + k] = v + bc[k];
  }
}

// ---------------------------------------------------------------- launch
extern "C" void kernel_launch(void* const* d_in, const int* in_sizes, int n_in,
                              void* d_out, int out_size, void* d_ws, size_t ws_size,
                              hipStream_t stream) {
  const float* features = (const float*)d_in[0];
  const int*   esrc     = (const int*)d_in[1];
  const int*   edst     = (const int*)d_in[2];
  const float* W1       = (const float*)d_in[3];
  const float* b1       = (const float*)d_in[4];
  const float* W2       = (const float*)d_in[5];
  const float* b2       = (const float*)d_in[6];
  const float* Wc       = (const float*)d_in[7];
  const float* bc       = (const float*)d_in[8];
  float* out = (float*)d_out;

  // ---- workspace layout (re-derived every call; ws poisoned 0xAA)
  int* deg_out = (int*)d_ws;                    // 50000
  int* deg_in  = deg_out + NNODES;              // 50000
  int* cursor  = deg_in + NNODES;               // 50000
  int* row_off = cursor + NNODES;               // 50001
  int* csr_src = row_off + NNODES + 1;          // 400000
  float* inv_s = (float*)(csr_src + NEDGES);    // 50000
  float* inv_d = inv_s + NNODES;                // 50000
  uintptr_t p16 = ((uintptr_t)(inv_d + NNODES) + 15) & ~(uintptr_t)15;
  uint32_t* hp = (uint32_t*)p16;                // [MP1][HID] packed h (rows>=NNODES unwritten: harmless, see epilogue guard)
  float* bufA = (float*)(hp + (size_t)MP1 * HID);  // [N,HID] gemm1 out, then [N,EMB] gemm2 out
  char*  Bp1  = (char*)(bufA + (size_t)NNODES * HID);   // 3*45 swizzled 16KB tiles
  char*  Bp2  = Bp1 + (size_t)3 * NKT1 * 16384;         // 2*12 swizzled 16KB tiles
  uint32_t* Ap = (uint32_t*)(Bp2 + (size_t)2 * NKT2 * 16384);  // [MP1][KP1] packed features

  size_t required = (uintptr_t)(Ap + (size_t)MP1 * KP1) - (uintptr_t)d_ws;
  bool use_mfma = ws_size >= required;

  // ---- graph prep
  hipMemsetAsync(deg_out, 0, 3 * NNODES * sizeof(int), stream);
  degree_kernel<<<1024, 256, 0, stream>>>(esrc, edst, deg_out, deg_in, NEDGES);
  inv_kernel<<<(NNODES + 255) / 256, 256, 0, stream>>>(deg_out, deg_in, inv_s, inv_d, NNODES);
  scan_kernel<<<1, 1024, 0, stream>>>(deg_in, row_off, NNODES);
  fill_csr<<<1024, 256, 0, stream>>>(esrc, edst, row_off, cursor, csr_src, NEDGES);

  if (use_mfma) {
    // ---- layer 1: bufA = inv_s * (X@W1);  hp = pack(relu(inv_d*gather(bufA)+b1))
    convA<<<dim3((KP1 / 4 + 255) / 256, MP1), 256, 0, stream>>>(features, Ap);
    convB<INF, HID, NKT1><<<dim3(NKT1, 3), 256, 0, stream>>>(W1, Bp1);
    gemm_mfma<KP1, HID, 3, NKT1><<<3 * NRB, 256, 0, stream>>>(Ap, Bp1, bufA, inv_s);
    gather_pack<<<(NNODES + 3) / 4, 256, 0, stream>>>(
        row_off, csr_src, bufA, inv_d, b1, hp, NNODES);

    // ---- layer 2: bufA = inv_s * (h@W2)   (MFMA; A already packed by gather_pack)
    convB<HID, EMB, NKT2><<<dim3(NKT2, 2), 256, 0, stream>>>(W2, Bp2);
    gemm_mfma<HID, EMB, 2, NKT2><<<2 * NRB, 256, 0, stream>>>(hp, Bp2, bufA, inv_s);
  } else {
    // ---- fallback: full fp32 path
    gemm_scale<16><<<dim3(HID / 128, (NNODES + 127) / 128), 256, 0, stream>>>(
        features, W1, bufA, inv_s, NNODES, HID, INF);
    gather_nodes<HID, true><<<(NNODES + 3) / 4, 256, 0, stream>>>(
        row_off, csr_src, bufA, inv_d, b1, (float*)hp, NNODES);
    gemm_scale<16><<<dim3(EMB / 128, (NNODES + 127) / 128), 256, 0, stream>>>(
        (float*)hp, W2, bufA, inv_s, NNODES, EMB, HID);
  }

  // ---- classifier (fused layer-2 epilogue + gather)
  gather_classifier<<<(NNODES + 3) / 4, 256, 0, stream>>>(
      row_off, csr_src, bufA, inv_d, b2, Wc, bc, out, NNODES);
}

// Round 7
// 940.446 us; speedup vs baseline: 1.4872x; 1.1016x over previous
//
#include <hip/hip_runtime.h>
#include <math.h>
#include <stdint.h>

constexpr int NNODES = 50000;
constexpr int NEDGES = 400000;
constexpr int INF = 1433;
constexpr int KP1 = 1440;          // INF padded to multiple of 32
constexpr int MP1 = 50048;         // NNODES padded to multiple of 128
constexpr int NRB = MP1 / 128;     // 391 row blocks
constexpr int NKT1 = KP1 / 32;     // 45 k-tiles (layer 1)
constexpr int HID = 384;
constexpr int NKT2 = HID / 32;     // 12 k-tiles (layer 2)
constexpr int EMB = 256;
constexpr int NCLS = 7;
constexpr int NSB = (NNODES + 255) / 256;   // 196 scan blocks

typedef __attribute__((ext_vector_type(8))) short bf16x8_t;   // 8 bf16 in 4 VGPRs
typedef __attribute__((ext_vector_type(4))) float f32x4_t;    // MFMA accumulator

typedef __attribute__((address_space(3))) uint32_t lds_u32_t;
typedef const __attribute__((address_space(1))) uint32_t glb_u32_t;

// ---------------------------------------------------------------- degrees
__global__ void degree_kernel(const int* __restrict__ src, const int* __restrict__ dst,
                              int* __restrict__ dout, int* __restrict__ din, int E) {
  int i = blockIdx.x * blockDim.x + threadIdx.x;
  int stride = gridDim.x * blockDim.x;
  for (; i < E; i += stride) {
    atomicAdd(&dout[src[i]], 1);
    atomicAdd(&din[dst[i]], 1);
  }
}

__global__ void inv_kernel(const int* __restrict__ dout, const int* __restrict__ din,
                           float* __restrict__ inv_s, float* __restrict__ inv_d, int N) {
  int i = blockIdx.x * blockDim.x + threadIdx.x;
  if (i < N) {
    inv_s[i] = 1.0f / sqrtf(fmaxf((float)dout[i], 1.0f));
    inv_d[i] = 1.0f / sqrtf(fmaxf((float)din[i], 1.0f));
  }
}

// ---------------------------------------------------------------- hierarchical exclusive scan
// s1: per-256-block scan (exclusive within block) + block sums
__global__ __launch_bounds__(256)
void scan_block(const int* __restrict__ deg, int* __restrict__ off,
                int* __restrict__ bsum, int N) {
  __shared__ int buf[256];
  int i = blockIdx.x * 256 + threadIdx.x;
  int v = (i < N) ? deg[i] : 0;
  buf[threadIdx.x] = v;
  __syncthreads();
  #pragma unroll
  for (int d = 1; d < 256; d <<= 1) {
    int t = (threadIdx.x >= d) ? buf[threadIdx.x - d] : 0;
    __syncthreads();
    buf[threadIdx.x] += t;
    __syncthreads();
  }
  if (i < N) off[i] = buf[threadIdx.x] - v;        // exclusive
  if (threadIdx.x == 255) bsum[blockIdx.x] = buf[255];
}

// s2: scan the 196 block sums (single small block); also writes off[N] = total
__global__ __launch_bounds__(256)
void scan_tops(const int* __restrict__ bsum, int* __restrict__ boff,
               int* __restrict__ off, int nb, int N) {
  __shared__ int buf[256];
  int v = (threadIdx.x < nb) ? bsum[threadIdx.x] : 0;
  buf[threadIdx.x] = v;
  __syncthreads();
  #pragma unroll
  for (int d = 1; d < 256; d <<= 1) {
    int t = (threadIdx.x >= d) ? buf[threadIdx.x - d] : 0;
    __syncthreads();
    buf[threadIdx.x] += t;
    __syncthreads();
  }
  if (threadIdx.x < nb) boff[threadIdx.x] = buf[threadIdx.x] - v;
  if (threadIdx.x == 255) off[N] = buf[255];       // grand total
}

// s3: add block offsets
__global__ __launch_bounds__(256)
void scan_add(const int* __restrict__ boff, int* __restrict__ off, int N) {
  int i = blockIdx.x * 256 + threadIdx.x;
  if (i < N) off[i] += boff[blockIdx.x];
}

__global__ void fill_csr(const int* __restrict__ src, const int* __restrict__ dst,
                         const int* __restrict__ off, int* __restrict__ cursor,
                         int* __restrict__ csr_src, int E) {
  int i = blockIdx.x * blockDim.x + threadIdx.x;
  int stride = gridDim.x * blockDim.x;
  for (; i < E; i += stride) {
    int d = dst[i];
    int p = atomicAdd(&cursor[d], 1);
    csr_src[off[d] + p] = src[i];
  }
}

// ---------------------------------------------------------------- split helpers
__device__ __forceinline__ uint32_t split_pack(float v) {
  uint32_t u = __float_as_uint(v);
  float hiF = __uint_as_float(u & 0xFFFF0000u);
  uint32_t u2 = __float_as_uint(v - hiF);
  return (u2 & 0xFFFF0000u) | (u >> 16);        // lo<<16 | hi
}

// ---------------------------------------------------------------- A pre-pack: fp32 -> hi|lo dword, [MP1][KP1]
__global__ void convA(const float* __restrict__ A, uint32_t* __restrict__ Ap) {
  int k4 = blockIdx.x * 256 + threadIdx.x;
  int r = blockIdx.y;
  if (k4 >= KP1 / 4) return;
  int k = k4 * 4;
  uint4 o = {0, 0, 0, 0};
  if (r < NNODES) {
    const float* row = A + (size_t)r * INF;
    if (k + 3 < INF) {
      float a0 = row[k], a1 = row[k + 1], a2 = row[k + 2], a3 = row[k + 3];
      o.x = split_pack(a0); o.y = split_pack(a1); o.z = split_pack(a2); o.w = split_pack(a3);
    } else {
      if (k + 0 < INF) o.x = split_pack(row[k + 0]);
      if (k + 1 < INF) o.y = split_pack(row[k + 1]);
      if (k + 2 < INF) o.z = split_pack(row[k + 2]);
      if (k + 3 < INF) o.w = split_pack(row[k + 3]);
    }
  }
  *(uint4*)&Ap[(size_t)r * KP1 + k] = o;   // row stride 5760B: 16B-aligned
}

// ---------------------------------------------------------------- W -> swizzled B tile images
// layout: [cb][T] tiles of 16KB; tile = hi-plane 8KB + lo-plane 8KB;
// within plane, (c,kk) at byte (c*64 + kk*2) ^ ((c&7)<<4)   (verified R4)
template<int KDIM, int NDIM, int NKTILES>
__global__ void convB(const float* __restrict__ W, char* __restrict__ Bp) {
  int T = blockIdx.x, cb = blockIdx.y;
  int kk = threadIdx.x & 31, c0 = threadIdx.x >> 5;
  char* tile = Bp + ((size_t)cb * NKTILES + T) * 16384;
  int gk = T * 32 + kk;
  #pragma unroll
  for (int i = 0; i < 16; ++i) {
    int c = c0 + i * 8;
    float v = (gk < KDIM) ? W[(size_t)gk * NDIM + cb * 128 + c] : 0.f;
    uint32_t p = split_pack(v);
    int bo = (c * 64 + kk * 2) ^ ((c & 7) << 4);
    *(ushort*)(tile + bo)        = (ushort)(p & 0xFFFFu);   // hi
    *(ushort*)(tile + 8192 + bo) = (ushort)(p >> 16);       // lo
  }
}

// ---------------------------------------------------------------- split-bf16 MFMA GEMM (verified R4/R5)
// C[M,NOUT] = (A@B) * scale[row]; 3-term split (ah*bh + ah*bl + al*bh).
// 128x128 tile, 4 waves, global_load_lds staging, pre-swizzled sources.
// Reg diet: 32-bit A offsets (saddr+voffset form) instead of 64-bit per-lane addrs.
template<int KPD, int NOUT, int NCOLB, int NKTILES>
__global__ __launch_bounds__(256, 2)
void gemm_mfma(const uint32_t* __restrict__ Ap, const char* __restrict__ Bp,
               float* __restrict__ C, const float* __restrict__ scale)
{
  __shared__ __align__(16) char sA[16384];   // [128 r][32 kk] dwords, XOR ((r&7)<<4) on byte addr
  __shared__ __align__(16) char sB[16384];   // swizzled tile image (hi 8KB + lo 8KB)

  // bijective XCD chunk remap (m204)
  constexpr int NWG = NCOLB * NRB;
  constexpr int q = NWG / 8, rr = NWG % 8;
  int orig = blockIdx.x;
  int xcd = orig & 7, sub = orig >> 3;
  int logical = (xcd < rr ? xcd * (q + 1) : rr * (q + 1) + (xcd - rr) * q) + sub;
  int bx = logical % NCOLB;
  int by = logical / NCOLB;
  const int row0 = by * 128, col0 = bx * 128;

  const int tid = threadIdx.x;
  const int w = tid >> 6, l = tid & 63;
  const int wr = w >> 1, wc = w & 1;
  const int lane15 = l & 15, kg = l >> 4;

  // per-lane pre-swizzled A source offsets, 32-bit (max 288MB < 4GB)
  uint32_t a_off[4];
  #pragma unroll
  for (int i = 0; i < 4; ++i) {
    int p = w * 4096 + i * 1024 + l * 16;
    int r = p >> 7;
    int kb = (p & 127) ^ ((r & 7) << 4);
    a_off[i] = (uint32_t)(row0 + r) * (KPD * 4) + kb;
  }
  const char* Ab = (const char*)Ap;
  const char* Btile = Bp + (size_t)(bx * NKTILES) * 16384;

  f32x4_t acc[4][4];
  #pragma unroll
  for (int mi = 0; mi < 4; ++mi)
    #pragma unroll
    for (int ni = 0; ni < 4; ++ni) acc[mi][ni] = {0.f, 0.f, 0.f, 0.f};

  for (int T = 0; T < NKTILES; ++T) {
    // ---- stage tiles: pure async copies, zero registers held
    #pragma unroll
    for (int i = 0; i < 4; ++i) {
      __builtin_amdgcn_global_load_lds(
          (glb_u32_t*)(Ab + (size_t)(a_off[i] + (uint32_t)T * 128u)),
          (lds_u32_t*)(sA + w * 4096 + i * 1024), 16, 0, 0);
    }
    #pragma unroll
    for (int i = 0; i < 4; ++i) {
      int p = w * 4096 + i * 1024;
      __builtin_amdgcn_global_load_lds(
          (glb_u32_t*)(Btile + (size_t)T * 16384 + p + l * 16),
          (lds_u32_t*)(sB + p), 16, 0, 0);
    }
    __syncthreads();   // drains vmcnt -> tiles visible

    // ---- B fragments (hi/lo planes, swizzled read)
    bf16x8_t bh[4], bl[4];
    #pragma unroll
    for (int ni = 0; ni < 4; ++ni) {
      int c = wc * 64 + ni * 16 + lane15;
      int bo = (c * 64 + kg * 16) ^ ((c & 7) << 4);
      bh[ni] = *(const bf16x8_t*)(sB + bo);
      bl[ni] = *(const bf16x8_t*)(sB + 8192 + bo);
    }
    // ---- A fragments per mi, unzip hi/lo, 3-term MFMA
    #pragma unroll
    for (int mi = 0; mi < 4; ++mi) {
      int ra = wr * 64 + mi * 16 + lane15;
      int a0 = (ra * 128 + kg * 32) ^ ((ra & 7) << 4);
      uint4 d0 = *(const uint4*)(sA + a0);
      uint4 d1 = *(const uint4*)(sA + (a0 ^ 16));
      union { uint32_t u[4]; bf16x8_t v; } th, tl;
      th.u[0] = (d0.x & 0xFFFFu) | (d0.y << 16);
      th.u[1] = (d0.z & 0xFFFFu) | (d0.w << 16);
      th.u[2] = (d1.x & 0xFFFFu) | (d1.y << 16);
      th.u[3] = (d1.z & 0xFFFFu) | (d1.w << 16);
      tl.u[0] = (d0.x >> 16) | (d0.y & 0xFFFF0000u);
      tl.u[1] = (d0.z >> 16) | (d0.w & 0xFFFF0000u);
      tl.u[2] = (d1.x >> 16) | (d1.y & 0xFFFF0000u);
      tl.u[3] = (d1.z >> 16) | (d1.w & 0xFFFF0000u);
      #pragma unroll
      for (int ni = 0; ni < 4; ++ni) {
        acc[mi][ni] = __builtin_amdgcn_mfma_f32_16x16x32_bf16(th.v, bh[ni], acc[mi][ni], 0, 0, 0);
        acc[mi][ni] = __builtin_amdgcn_mfma_f32_16x16x32_bf16(th.v, bl[ni], acc[mi][ni], 0, 0, 0);
        acc[mi][ni] = __builtin_amdgcn_mfma_f32_16x16x32_bf16(tl.v, bh[ni], acc[mi][ni], 0, 0, 0);
      }
    }
    __syncthreads();   // all reads done before next tile overwrites
  }

  // ---- epilogue: D row=(l>>4)*4+j, col=l&15 (verified); scale rows
  #pragma unroll
  for (int mi = 0; mi < 4; ++mi) {
    #pragma unroll
    for (int j = 0; j < 4; ++j) {
      int gr = row0 + wr * 64 + mi * 16 + kg * 4 + j;
      if (gr >= NNODES) continue;
      float s = scale[gr];
      #pragma unroll
      for (int ni = 0; ni < 4; ++ni) {
        int gc = col0 + wc * 64 + ni * 16 + lane15;
        C[(size_t)gr * NOUT + gc] = acc[mi][ni][j] * s;
      }
    }
  }
}

// ---------------------------------------------------------------- fp32 GEMM (fallback only)
template<int BK>
__global__ __launch_bounds__(256)
void gemm_scale(const float* __restrict__ A, const float* __restrict__ B,
                float* __restrict__ C, const float* __restrict__ scale,
                int M, int N, int K)
{
  constexpr int BM = 128, BN = 128;
  constexpr int LDA = BM + 4;
  constexpr int LDB = BN + 4;
  __shared__ float As[BK][LDA];
  __shared__ float Bs[BK][LDB];

  const int tid = threadIdx.x;
  const int tx = tid & 15;
  const int ty = tid >> 4;
  const int row0 = blockIdx.y * BM;
  const int col0 = blockIdx.x * BN;

  float acc[8][8];
  #pragma unroll
  for (int i = 0; i < 8; ++i)
    #pragma unroll
    for (int j = 0; j < 8; ++j) acc[i][j] = 0.f;

  for (int kt = 0; kt < K; kt += BK) {
    #pragma unroll
    for (int p = 0; p < BM / 16; ++p) {
      int r = (tid >> 4) + p * 16;
      int k = tid & 15;
      int gr = row0 + r, gk = kt + k;
      float v = 0.f;
      if (gr < M && gk < K) v = A[(size_t)gr * K + gk];
      As[k][r] = v;
    }
    #pragma unroll
    for (int p = 0; p < BK / 8; ++p) {
      int r = (tid >> 5) + p * 8;
      int c4 = (tid & 31) * 4;
      int gk = kt + r;
      float4 v = {0.f, 0.f, 0.f, 0.f};
      if (gk < K) v = *(const float4*)&B[(size_t)gk * N + col0 + c4];
      *(float4*)&Bs[r][c4] = v;
    }
    __syncthreads();
    #pragma unroll
    for (int k = 0; k < BK; ++k) {
      float4 a0 = *(const float4*)&As[k][ty * 8];
      float4 a1 = *(const float4*)&As[k][ty * 8 + 4];
      float4 b0 = *(const float4*)&Bs[k][tx * 8];
      float4 b1 = *(const float4*)&Bs[k][tx * 8 + 4];
      float av[8] = {a0.x, a0.y, a0.z, a0.w, a1.x, a1.y, a1.z, a1.w};
      float bv[8] = {b0.x, b0.y, b0.z, b0.w, b1.x, b1.y, b1.z, b1.w};
      #pragma unroll
      for (int i = 0; i < 8; ++i)
        #pragma unroll
        for (int j = 0; j < 8; ++j)
          acc[i][j] = fmaf(av[i], bv[j], acc[i][j]);
    }
    __syncthreads();
  }
  #pragma unroll
  for (int i = 0; i < 8; ++i) {
    int gr = row0 + ty * 8 + i;
    if (gr >= M) continue;
    float s = scale[gr];
    #pragma unroll
    for (int j = 0; j < 8; j += 4) {
      float4 v = {acc[i][j] * s, acc[i][j + 1] * s, acc[i][j + 2] * s, acc[i][j + 3] * s};
      *(float4*)&C[(size_t)gr * N + col0 + tx * 8 + j] = v;
    }
  }
}

// ---------------------------------------------------------------- CSR gather, wave per node (fp32 out; fallback)
template<int NF, bool RELU>
__global__ __launch_bounds__(256)
void gather_nodes(const int* __restrict__ off, const int* __restrict__ csr_src,
                  const float* __restrict__ h, const float* __restrict__ inv_d,
                  const float* __restrict__ bias, float* __restrict__ outbuf, int N)
{
  int node = blockIdx.x * 4 + (threadIdx.x >> 6);
  int lane = threadIdx.x & 63;
  if (node >= N) return;
  constexpr int NI = NF / 128;
  float2 acc[NI];
  #pragma unroll
  for (int i = 0; i < NI; ++i) acc[i] = {0.f, 0.f};

  int e0 = off[node], e1 = off[node + 1];
  for (int e = e0; e < e1; ++e) {
    const float* hr = h + (size_t)csr_src[e] * NF;
    #pragma unroll
    for (int i = 0; i < NI; ++i) {
      float2 v = *(const float2*)&hr[lane * 2 + i * 128];
      acc[i].x += v.x; acc[i].y += v.y;
    }
  }
  float s = inv_d[node];
  float* orow = outbuf + (size_t)node * NF;
  #pragma unroll
  for (int i = 0; i < NI; ++i) {
    int f = lane * 2 + i * 128;
    float2 v;
    v.x = fmaf(acc[i].x, s, bias[f]);
    v.y = fmaf(acc[i].y, s, bias[f + 1]);
    if (RELU) { v.x = fmaxf(v.x, 0.f); v.y = fmaxf(v.y, 0.f); }
    *(float2*)&orow[f] = v;
  }
}

// ---------------------------------------------------------------- CSR gather -> relu -> PACKED hi|lo output
// 4-edge unroll: 4 index + 12 row loads issued independently (MLP for latency hiding)
__global__ __launch_bounds__(256)
void gather_pack(const int* __restrict__ off, const int* __restrict__ csr_src,
                 const float* __restrict__ h, const float* __restrict__ inv_d,
                 const float* __restrict__ bias, uint32_t* __restrict__ outp, int N)
{
  int node = blockIdx.x * 4 + (threadIdx.x >> 6);
  int lane = threadIdx.x & 63;
  if (node >= N) return;
  float2 acc[3];
  #pragma unroll
  for (int i = 0; i < 3; ++i) acc[i] = {0.f, 0.f};

  int e0 = off[node], e1 = off[node + 1];
  int e = e0;
  for (; e + 4 <= e1; e += 4) {
    const float* r0 = h + (size_t)csr_src[e + 0] * HID;
    const float* r1 = h + (size_t)csr_src[e + 1] * HID;
    const float* r2 = h + (size_t)csr_src[e + 2] * HID;
    const float* r3 = h + (size_t)csr_src[e + 3] * HID;
    #pragma unroll
    for (int i = 0; i < 3; ++i) {
      int f = lane * 2 + i * 128;
      float2 v0 = *(const float2*)&r0[f];
      float2 v1 = *(const float2*)&r1[f];
      float2 v2 = *(const float2*)&r2[f];
      float2 v3 = *(const float2*)&r3[f];
      acc[i].x += (v0.x + v1.x) + (v2.x + v3.x);
      acc[i].y += (v0.y + v1.y) + (v2.y + v3.y);
    }
  }
  for (; e < e1; ++e) {
    const float* hr = h + (size_t)csr_src[e] * HID;
    #pragma unroll
    for (int i = 0; i < 3; ++i) {
      float2 v = *(const float2*)&hr[lane * 2 + i * 128];
      acc[i].x += v.x; acc[i].y += v.y;
    }
  }
  float s = inv_d[node];
  uint32_t* orow = outp + (size_t)node * HID;
  #pragma unroll
  for (int i = 0; i < 3; ++i) {
    int f = lane * 2 + i * 128;
    float vx = fmaxf(fmaf(acc[i].x, s, bias[f]), 0.f);
    float vy = fmaxf(fmaf(acc[i].y, s, bias[f + 1]), 0.f);
    uint2 o = {split_pack(vx), split_pack(vy)};
    *(uint2*)&orow[f] = o;
  }
}

// ---------------------------------------------------------------- CSR gather + classifier fused (4-edge unroll)
__global__ __launch_bounds__(256)
void gather_classifier(const int* __restrict__ off, const int* __restrict__ csr_src,
                       const float* __restrict__ h, const float* __restrict__ inv_d,
                       const float* __restrict__ b2, const float* __restrict__ Wc,
                       const float* __restrict__ bc, float* __restrict__ out, int N)
{
  __shared__ float sWc[EMB * NCLS];
  for (int i = threadIdx.x; i < EMB * NCLS; i += 256) sWc[i] = Wc[i];
  __syncthreads();

  int node = blockIdx.x * 4 + (threadIdx.x >> 6);
  int lane = threadIdx.x & 63;
  if (node >= N) return;

  float2 acc[2] = {{0.f, 0.f}, {0.f, 0.f}};
  int e0 = off[node], e1 = off[node + 1];
  int e = e0;
  for (; e + 4 <= e1; e += 4) {
    const float* r0 = h + (size_t)csr_src[e + 0] * EMB;
    const float* r1 = h + (size_t)csr_src[e + 1] * EMB;
    const float* r2 = h + (size_t)csr_src[e + 2] * EMB;
    const float* r3 = h + (size_t)csr_src[e + 3] * EMB;
    #pragma unroll
    for (int i = 0; i < 2; ++i) {
      int f = lane * 2 + i * 128;
      float2 v0 = *(const float2*)&r0[f];
      float2 v1 = *(const float2*)&r1[f];
      float2 v2 = *(const float2*)&r2[f];
      float2 v3 = *(const float2*)&r3[f];
      acc[i].x += (v0.x + v1.x) + (v2.x + v3.x);
      acc[i].y += (v0.y + v1.y) + (v2.y + v3.y);
    }
  }
  for (; e < e1; ++e) {
    const float* hr = h + (size_t)csr_src[e] * EMB;
    #pragma unroll
    for (int i = 0; i < 2; ++i) {
      float2 v = *(const float2*)&hr[lane * 2 + i * 128];
      acc[i].x += v.x; acc[i].y += v.y;
    }
  }
  float s = inv_d[node];
  float c[NCLS];
  #pragma unroll
  for (int k = 0; k < NCLS; ++k) c[k] = 0.f;
  #pragma unroll
  for (int i = 0; i < 2; ++i) {
    int f = lane * 2 + i * 128;
    float hx = fmaf(acc[i].x, s, b2[f]);
    float hy = fmaf(acc[i].y, s, b2[f + 1]);
    #pragma unroll
    for (int k = 0; k < NCLS; ++k)
      c[k] += hx * sWc[f * NCLS + k] + hy * sWc[(f + 1) * NCLS + k];
  }
  #pragma unroll
  for (int k = 0; k < NCLS; ++k) {
    float v = c[k];
    #pragma unroll
    for (int o = 32; o > 0; o >>= 1) v += __shfl_down(v, o);
    if (lane == 0) out[(size_t)node * NCLS + k] = v + bc[k];
  }
}

// ---------------------------------------------------------------- launch
extern "C" void kernel_launch(void* const* d_in, const int* in_sizes, int n_in,
                              void* d_out, int out_size, void* d_ws, size_t ws_size,
                              hipStream_t stream) {
  const float* features = (const float*)d_in[0];
  const int*   esrc     = (const int*)d_in[1];
  const int*   edst     = (const int*)d_in[2];
  const float* W1       = (const float*)d_in[3];
  const float* b1       = (const float*)d_in[4];
  const float* W2       = (const float*)d_in[5];
  const float* b2       = (const float*)d_in[6];
  const float* Wc       = (const float*)d_in[7];
  const float* bc       = (const float*)d_in[8];
  float* out = (float*)d_out;

  // ---- workspace layout (re-derived every call; ws poisoned 0xAA)
  int* deg_out = (int*)d_ws;                    // 50000
  int* deg_in  = deg_out + NNODES;              // 50000
  int* cursor  = deg_in + NNODES;               // 50000
  int* row_off = cursor + NNODES;               // 50001
  int* csr_src = row_off + NNODES + 1;          // 400000
  int* bsum    = csr_src + NEDGES;              // 196
  int* boff    = bsum + NSB;                    // 196
  float* inv_s = (float*)(boff + NSB);          // 50000
  float* inv_d = inv_s + NNODES;                // 50000
  uintptr_t p16 = ((uintptr_t)(inv_d + NNODES) + 15) & ~(uintptr_t)15;
  uint32_t* hp = (uint32_t*)p16;                // [MP1][HID] packed h
  float* bufA = (float*)(hp + (size_t)MP1 * HID);  // [N,HID] gemm1 out, then [N,EMB] gemm2 out
  char*  Bp1  = (char*)(bufA + (size_t)NNODES * HID);   // 3*45 swizzled 16KB tiles
  char*  Bp2  = Bp1 + (size_t)3 * NKT1 * 16384;         // 2*12 swizzled 16KB tiles
  uint32_t* Ap = (uint32_t*)(Bp2 + (size_t)2 * NKT2 * 16384);  // [MP1][KP1] packed features

  size_t required = (uintptr_t)(Ap + (size_t)MP1 * KP1) - (uintptr_t)d_ws;
  bool use_mfma = ws_size >= required;

  // ---- graph prep
  hipMemsetAsync(deg_out, 0, 3 * NNODES * sizeof(int), stream);
  degree_kernel<<<1024, 256, 0, stream>>>(esrc, edst, deg_out, deg_in, NEDGES);
  inv_kernel<<<(NNODES + 255) / 256, 256, 0, stream>>>(deg_out, deg_in, inv_s, inv_d, NNODES);
  scan_block<<<NSB, 256, 0, stream>>>(deg_in, row_off, bsum, NNODES);
  scan_tops<<<1, 256, 0, stream>>>(bsum, boff, row_off, NSB, NNODES);
  scan_add<<<NSB, 256, 0, stream>>>(boff, row_off, NNODES);
  fill_csr<<<1024, 256, 0, stream>>>(esrc, edst, row_off, cursor, csr_src, NEDGES);

  if (use_mfma) {
    // ---- layer 1: bufA = inv_s * (X@W1);  hp = pack(relu(inv_d*gather(bufA)+b1))
    convA<<<dim3((KP1 / 4 + 255) / 256, MP1), 256, 0, stream>>>(features, Ap);
    convB<INF, HID, NKT1><<<dim3(NKT1, 3), 256, 0, stream>>>(W1, Bp1);
    gemm_mfma<KP1, HID, 3, NKT1><<<3 * NRB, 256, 0, stream>>>(Ap, Bp1, bufA, inv_s);
    gather_pack<<<(NNODES + 3) / 4, 256, 0, stream>>>(
        row_off, csr_src, bufA, inv_d, b1, hp, NNODES);

    // ---- layer 2: bufA = inv_s * (h@W2)   (MFMA; A already packed by gather_pack)
    convB<HID, EMB, NKT2><<<dim3(NKT2, 2), 256, 0, stream>>>(W2, Bp2);
    gemm_mfma<HID, EMB, 2, NKT2><<<2 * NRB, 256, 0, stream>>>(hp, Bp2, bufA, inv_s);
  } else {
    // ---- fallback: full fp32 path
    gemm_scale<16><<<dim3(HID / 128, (NNODES + 127) / 128), 256, 0, stream>>>(
        features, W1, bufA, inv_s, NNODES, HID, INF);
    gather_nodes<HID, true><<<(NNODES + 3) / 4, 256, 0, stream>>>(
        row_off, csr_src, bufA, inv_d, b1, (float*)hp, NNODES);
    gemm_scale<16><<<dim3(EMB / 128, (NNODES + 127) / 128), 256, 0, stream>>>(
        (float*)hp, W2, bufA, inv_s, NNODES, EMB, HID);
  }

  // ---- classifier (fused layer-2 epilogue + gather)
  gather_classifier<<<(NNODES + 3) / 4, 256, 0, stream>>>(
      row_off, csr_src, bufA, inv_d, b2, Wc, bc, out, NNODES);
}

// Round 9
// 839.834 us; speedup vs baseline: 1.6654x; 1.1198x over previous
//
#include <hip/hip_runtime.h>
#include <math.h>
#include <stdint.h>

constexpr int NNODES = 50000;
constexpr int NEDGES = 400000;
constexpr int INF = 1433;
constexpr int KP1 = 1440;          // INF padded to multiple of 32
constexpr int MP1 = 50048;         // NNODES padded to multiple of 128
constexpr int NRB = MP1 / 128;     // 391 row blocks
constexpr int NKT1 = KP1 / 32;     // 45 k-tiles (layer 1)
constexpr int HID = 384;
constexpr int NKT2 = HID / 32;     // 12 k-tiles (layer 2)
constexpr int EMB = 256;
constexpr int NCLS = 7;
constexpr int NSB = (NNODES + 255) / 256;   // 196 scan blocks

typedef __attribute__((ext_vector_type(8))) short bf16x8_t;   // 8 bf16 in 4 VGPRs
typedef __attribute__((ext_vector_type(4))) float f32x4_t;    // MFMA accumulator

typedef __attribute__((address_space(3))) uint32_t lds_u32_t;
typedef const __attribute__((address_space(1))) uint32_t glb_u32_t;

// ---------------------------------------------------------------- degrees
__global__ void degree_kernel(const int* __restrict__ src, const int* __restrict__ dst,
                              int* __restrict__ dout, int* __restrict__ din, int E) {
  int i = blockIdx.x * blockDim.x + threadIdx.x;
  int stride = gridDim.x * blockDim.x;
  for (; i < E; i += stride) {
    atomicAdd(&dout[src[i]], 1);
    atomicAdd(&din[dst[i]], 1);
  }
}

__global__ void inv_kernel(const int* __restrict__ dout, const int* __restrict__ din,
                           float* __restrict__ inv_s, float* __restrict__ inv_d, int N) {
  int i = blockIdx.x * blockDim.x + threadIdx.x;
  if (i < N) {
    inv_s[i] = 1.0f / sqrtf(fmaxf((float)dout[i], 1.0f));
    inv_d[i] = 1.0f / sqrtf(fmaxf((float)din[i], 1.0f));
  }
}

// ---------------------------------------------------------------- hierarchical exclusive scan
__global__ __launch_bounds__(256)
void scan_block(const int* __restrict__ deg, int* __restrict__ off,
                int* __restrict__ bsum, int N) {
  __shared__ int buf[256];
  int i = blockIdx.x * 256 + threadIdx.x;
  int v = (i < N) ? deg[i] : 0;
  buf[threadIdx.x] = v;
  __syncthreads();
  #pragma unroll
  for (int d = 1; d < 256; d <<= 1) {
    int t = (threadIdx.x >= d) ? buf[threadIdx.x - d] : 0;
    __syncthreads();
    buf[threadIdx.x] += t;
    __syncthreads();
  }
  if (i < N) off[i] = buf[threadIdx.x] - v;        // exclusive
  if (threadIdx.x == 255) bsum[blockIdx.x] = buf[255];
}

__global__ __launch_bounds__(256)
void scan_tops(const int* __restrict__ bsum, int* __restrict__ boff,
               int* __restrict__ off, int nb, int N) {
  __shared__ int buf[256];
  int v = (threadIdx.x < nb) ? bsum[threadIdx.x] : 0;
  buf[threadIdx.x] = v;
  __syncthreads();
  #pragma unroll
  for (int d = 1; d < 256; d <<= 1) {
    int t = (threadIdx.x >= d) ? buf[threadIdx.x - d] : 0;
    __syncthreads();
    buf[threadIdx.x] += t;
    __syncthreads();
  }
  if (threadIdx.x < nb) boff[threadIdx.x] = buf[threadIdx.x] - v;
  if (threadIdx.x == 255) off[N] = buf[255];       // grand total
}

__global__ __launch_bounds__(256)
void scan_add(const int* __restrict__ boff, int* __restrict__ off, int N) {
  int i = blockIdx.x * 256 + threadIdx.x;
  if (i < N) off[i] += boff[blockIdx.x];
}

__global__ void fill_csr(const int* __restrict__ src, const int* __restrict__ dst,
                         const int* __restrict__ off, int* __restrict__ cursor,
                         int* __restrict__ csr_src, int E) {
  int i = blockIdx.x * blockDim.x + threadIdx.x;
  int stride = gridDim.x * blockDim.x;
  for (; i < E; i += stride) {
    int d = dst[i];
    int p = atomicAdd(&cursor[d], 1);
    csr_src[off[d] + p] = src[i];
  }
}

// ---------------------------------------------------------------- split helpers
__device__ __forceinline__ uint32_t split_pack(float v) {
  uint32_t u = __float_as_uint(v);
  float hiF = __uint_as_float(u & 0xFFFF0000u);
  uint32_t u2 = __float_as_uint(v - hiF);
  return (u2 & 0xFFFF0000u) | (u >> 16);        // lo<<16 | hi
}

// ---------------------------------------------------------------- W -> swizzled B tile images
// layout: [cb][T] tiles of 16KB; tile = hi-plane 8KB + lo-plane 8KB;
// within plane, (c,kk) at byte (c*64 + kk*2) ^ ((c&7)<<4)   (verified R4)
template<int KDIM, int NDIM, int NKTILES>
__global__ void convB(const float* __restrict__ W, char* __restrict__ Bp) {
  int T = blockIdx.x, cb = blockIdx.y;
  int kk = threadIdx.x & 31, c0 = threadIdx.x >> 5;
  char* tile = Bp + ((size_t)cb * NKTILES + T) * 16384;
  int gk = T * 32 + kk;
  #pragma unroll
  for (int i = 0; i < 16; ++i) {
    int c = c0 + i * 8;
    float v = (gk < KDIM) ? W[(size_t)gk * NDIM + cb * 128 + c] : 0.f;
    uint32_t p = split_pack(v);
    int bo = (c * 64 + kk * 2) ^ ((c & 7) << 4);
    *(ushort*)(tile + bo)        = (ushort)(p & 0xFFFFu);   // hi
    *(ushort*)(tile + 8192 + bo) = (ushort)(p >> 16);       // lo
  }
}

// ---------------------------------------------------------------- split-bf16 MFMA GEMM (verified R4/R5/R7 core)
// C[M,NOUT] = (A@B) * scale[row]; 3-term split (ah*bh + ah*bl + al*bh).
// RAW=false: A is packed hi|lo dwords (row stride AROWB bytes), width-16 staging.
// RAW=true : A is raw fp32 (features, row stride AROWB=5732, 4B-aligned only):
//            width-4 staging + in-register truncation split at fragment read.
template<int AROWB, int NOUT, int NCOLB, int NKTILES, bool RAW>
__global__ __launch_bounds__(256, 2)
void gemm_mfma(const char* __restrict__ Ab, const char* __restrict__ Bp,
               float* __restrict__ C, const float* __restrict__ scale)
{
  __shared__ __align__(16) char sA[16384];   // [128 r][32 k] dwords, XOR ((r&7)<<4) on byte addr
  __shared__ __align__(16) char sB[16384];   // swizzled tile image (hi 8KB + lo 8KB)

  // bijective XCD chunk remap (m204)
  constexpr int NWG = NCOLB * NRB;
  constexpr int q = NWG / 8, rr = NWG % 8;
  int orig = blockIdx.x;
  int xcd = orig & 7, sub = orig >> 3;
  int logical = (xcd < rr ? xcd * (q + 1) : rr * (q + 1) + (xcd - rr) * q) + sub;
  int bx = logical % NCOLB;
  int by = logical / NCOLB;
  int row0 = by * 128;
  if (RAW) row0 = min(row0, NNODES - 128);   // last block shifts down: all rows valid,
                                             // rows 49872..49919 written twice (same values)
  const int col0 = bx * 128;

  const int tid = threadIdx.x;
  const int w = tid >> 6, l = tid & 63;
  const int wr = w >> 1, wc = w & 1;
  const int lane15 = l & 15, kg = l >> 4;

  // per-lane pre-swizzled A source offsets (u32; A < 4GB), rule-21 pattern
  uint32_t a_base[4];
  if constexpr (RAW) {
    // width-4: LDS pos p = w*4096 + jj*256 + l*4; r = w*32 + jj*2 + (l>>5);
    // p&127 = (l&31)*4; source col byte = (p&127) ^ ((r&7)<<4). Affine in jj with
    // period 4 (r&7 invariant under jj+=4 since row += 8).
    int lb = l >> 5, col4 = (l & 31) * 4;
    #pragma unroll
    for (int j0 = 0; j0 < 4; ++j0) {
      int r = w * 32 + j0 * 2 + lb;
      a_base[j0] = (uint32_t)(row0 + r) * (uint32_t)AROWB
                 + (uint32_t)(col4 ^ ((r & 7) << 4));
    }
  } else {
    #pragma unroll
    for (int i = 0; i < 4; ++i) {
      int p = w * 4096 + i * 1024 + l * 16;
      int r = p >> 7;
      int kb = (p & 127) ^ ((r & 7) << 4);
      a_base[i] = (uint32_t)(row0 + r) * (uint32_t)AROWB + (uint32_t)kb;
    }
  }
  const char* Btile = Bp + (size_t)(bx * NKTILES) * 16384;

  f32x4_t acc[4][4];
  #pragma unroll
  for (int mi = 0; mi < 4; ++mi)
    #pragma unroll
    for (int ni = 0; ni < 4; ++ni) acc[mi][ni] = {0.f, 0.f, 0.f, 0.f};

  for (int T = 0; T < NKTILES; ++T) {
    // ---- stage A (async, zero registers held across barrier)
    if constexpr (RAW) {
      #pragma unroll
      for (int jj = 0; jj < 16; ++jj) {
        __builtin_amdgcn_global_load_lds(
            (glb_u32_t*)(Ab + (size_t)(a_base[jj & 3]
                                       + (uint32_t)((jj >> 2) * 8 * AROWB)
                                       + (uint32_t)T * 128u)),
            (lds_u32_t*)(sA + w * 4096 + jj * 256), 4, 0, 0);
      }
    } else {
      #pragma unroll
      for (int i = 0; i < 4; ++i) {
        __builtin_amdgcn_global_load_lds(
            (glb_u32_t*)(Ab + (size_t)(a_base[i] + (uint32_t)T * 128u)),
            (lds_u32_t*)(sA + w * 4096 + i * 1024), 16, 0, 0);
      }
    }
    // ---- stage B (swizzled tile image, pure linear copy)
    #pragma unroll
    for (int i = 0; i < 4; ++i) {
      int p = w * 4096 + i * 1024;
      __builtin_amdgcn_global_load_lds(
          (glb_u32_t*)(Btile + (size_t)T * 16384 + p + l * 16),
          (lds_u32_t*)(sB + p), 16, 0, 0);
    }
    __syncthreads();   // drains vmcnt -> tiles visible

    // ---- B fragments (hi/lo planes, swizzled read)
    bf16x8_t bh[4], bl[4];
    #pragma unroll
    for (int ni = 0; ni < 4; ++ni) {
      int c = wc * 64 + ni * 16 + lane15;
      int bo = (c * 64 + kg * 16) ^ ((c & 7) << 4);
      bh[ni] = *(const bf16x8_t*)(sB + bo);
      bl[ni] = *(const bf16x8_t*)(sB + 8192 + bo);
    }
    // ---- A fragments per mi, hi/lo planes, 3-term MFMA
    #pragma unroll
    for (int mi = 0; mi < 4; ++mi) {
      int ra = wr * 64 + mi * 16 + lane15;
      int a0 = (ra * 128 + kg * 32) ^ ((ra & 7) << 4);
      uint4 d0 = *(const uint4*)(sA + a0);
      uint4 d1 = *(const uint4*)(sA + (a0 ^ 16));
      union { uint32_t u[4]; bf16x8_t v; } th, tl;
      if constexpr (RAW) {
        // raw fp32: truncation split in-register (matches split_pack numerics)
        uint32_t uu[8] = {d0.x, d0.y, d0.z, d0.w, d1.x, d1.y, d1.z, d1.w};
        #pragma unroll
        for (int pp = 0; pp < 4; ++pp) {
          uint32_t ux = uu[2 * pp], uy = uu[2 * pp + 1];
          uint32_t hx = ux & 0xFFFF0000u, hy = uy & 0xFFFF0000u;
          uint32_t lx = __float_as_uint(__uint_as_float(ux) - __uint_as_float(hx));
          uint32_t ly = __float_as_uint(__uint_as_float(uy) - __uint_as_float(hy));
          th.u[pp] = (ux >> 16) | hy;
          tl.u[pp] = (lx >> 16) | (ly & 0xFFFF0000u);
        }
      } else {
        th.u[0] = (d0.x & 0xFFFFu) | (d0.y << 16);
        th.u[1] = (d0.z & 0xFFFFu) | (d0.w << 16);
        th.u[2] = (d1.x & 0xFFFFu) | (d1.y << 16);
        th.u[3] = (d1.z & 0xFFFFu) | (d1.w << 16);
        tl.u[0] = (d0.x >> 16) | (d0.y & 0xFFFF0000u);
        tl.u[1] = (d0.z >> 16) | (d0.w & 0xFFFF0000u);
        tl.u[2] = (d1.x >> 16) | (d1.y & 0xFFFF0000u);
        tl.u[3] = (d1.z >> 16) | (d1.w & 0xFFFF0000u);
      }
      #pragma unroll
      for (int ni = 0; ni < 4; ++ni) {
        acc[mi][ni] = __builtin_amdgcn_mfma_f32_16x16x32_bf16(th.v, bh[ni], acc[mi][ni], 0, 0, 0);
        acc[mi][ni] = __builtin_amdgcn_mfma_f32_16x16x32_bf16(th.v, bl[ni], acc[mi][ni], 0, 0, 0);
        acc[mi][ni] = __builtin_amdgcn_mfma_f32_16x16x32_bf16(tl.v, bh[ni], acc[mi][ni], 0, 0, 0);
      }
    }
    __syncthreads();   // all reads done before next tile overwrites
  }

  // ---- epilogue: D row=(l>>4)*4+j, col=l&15 (verified); scale rows
  #pragma unroll
  for (int mi = 0; mi < 4; ++mi) {
    #pragma unroll
    for (int j = 0; j < 4; ++j) {
      int gr = row0 + wr * 64 + mi * 16 + kg * 4 + j;
      if (gr >= NNODES) continue;
      float s = scale[gr];
      #pragma unroll
      for (int ni = 0; ni < 4; ++ni) {
        int gc = col0 + wc * 64 + ni * 16 + lane15;
        C[(size_t)gr * NOUT + gc] = acc[mi][ni][j] * s;
      }
    }
  }
}

// ---------------------------------------------------------------- fp32 GEMM (fallback only)
template<int BK>
__global__ __launch_bounds__(256)
void gemm_scale(const float* __restrict__ A, const float* __restrict__ B,
                float* __restrict__ C, const float* __restrict__ scale,
                int M, int N, int K)
{
  constexpr int BM = 128, BN = 128;
  constexpr int LDA = BM + 4;
  constexpr int LDB = BN + 4;
  __shared__ float As[BK][LDA];
  __shared__ float Bs[BK][LDB];

  const int tid = threadIdx.x;
  const int tx = tid & 15;
  const int ty = tid >> 4;
  const int row0 = blockIdx.y * BM;
  const int col0 = blockIdx.x * BN;

  float acc[8][8];
  #pragma unroll
  for (int i = 0; i < 8; ++i)
    #pragma unroll
    for (int j = 0; j < 8; ++j) acc[i][j] = 0.f;

  for (int kt = 0; kt < K; kt += BK) {
    #pragma unroll
    for (int p = 0; p < BM / 16; ++p) {
      int r = (tid >> 4) + p * 16;
      int k = tid & 15;
      int gr = row0 + r, gk = kt + k;
      float v = 0.f;
      if (gr < M && gk < K) v = A[(size_t)gr * K + gk];
      As[k][r] = v;
    }
    #pragma unroll
    for (int p = 0; p < BK / 8; ++p) {
      int r = (tid >> 5) + p * 8;
      int c4 = (tid & 31) * 4;
      int gk = kt + r;
      float4 v = {0.f, 0.f, 0.f, 0.f};
      if (gk < K) v = *(const float4*)&B[(size_t)gk * N + col0 + c4];
      *(float4*)&Bs[r][c4] = v;
    }
    __syncthreads();
    #pragma unroll
    for (int k = 0; k < BK; ++k) {
      float4 a0 = *(const float4*)&As[k][ty * 8];
      float4 a1 = *(const float4*)&As[k][ty * 8 + 4];
      float4 b0 = *(const float4*)&Bs[k][tx * 8];
      float4 b1 = *(const float4*)&Bs[k][tx * 8 + 4];
      float av[8] = {a0.x, a0.y, a0.z, a0.w, a1.x, a1.y, a1.z, a1.w};
      float bv[8] = {b0.x, b0.y, b0.z, b0.w, b1.x, b1.y, b1.z, b1.w};
      #pragma unroll
      for (int i = 0; i < 8; ++i)
        #pragma unroll
        for (int j = 0; j < 8; ++j)
          acc[i][j] = fmaf(av[i], bv[j], acc[i][j]);
    }
    __syncthreads();
  }
  #pragma unroll
  for (int i = 0; i < 8; ++i) {
    int gr = row0 + ty * 8 + i;
    if (gr >= M) continue;
    float s = scale[gr];
    #pragma unroll
    for (int j = 0; j < 8; j += 4) {
      float4 v = {acc[i][j] * s, acc[i][j + 1] * s, acc[i][j + 2] * s, acc[i][j + 3] * s};
      *(float4*)&C[(size_t)gr * N + col0 + tx * 8 + j] = v;
    }
  }
}

// ---------------------------------------------------------------- CSR gather, wave per node (fp32 out; fallback)
template<int NF, bool RELU>
__global__ __launch_bounds__(256)
void gather_nodes(const int* __restrict__ off, const int* __restrict__ csr_src,
                  const float* __restrict__ h, const float* __restrict__ inv_d,
                  const float* __restrict__ bias, float* __restrict__ outbuf, int N)
{
  int node = blockIdx.x * 4 + (threadIdx.x >> 6);
  int lane = threadIdx.x & 63;
  if (node >= N) return;
  constexpr int NI = NF / 128;
  float2 acc[NI];
  #pragma unroll
  for (int i = 0; i < NI; ++i) acc[i] = {0.f, 0.f};

  int e0 = off[node], e1 = off[node + 1];
  for (int e = e0; e < e1; ++e) {
    const float* hr = h + (size_t)csr_src[e] * NF;
    #pragma unroll
    for (int i = 0; i < NI; ++i) {
      float2 v = *(const float2*)&hr[lane * 2 + i * 128];
      acc[i].x += v.x; acc[i].y += v.y;
    }
  }
  float s = inv_d[node];
  float* orow = outbuf + (size_t)node * NF;
  #pragma unroll
  for (int i = 0; i < NI; ++i) {
    int f = lane * 2 + i * 128;
    float2 v;
    v.x = fmaf(acc[i].x, s, bias[f]);
    v.y = fmaf(acc[i].y, s, bias[f + 1]);
    if (RELU) { v.x = fmaxf(v.x, 0.f); v.y = fmaxf(v.y, 0.f); }
    *(float2*)&orow[f] = v;
  }
}

// ---------------------------------------------------------------- CSR gather -> relu -> PACKED hi|lo output
// 4-edge unroll (verified R7)
__global__ __launch_bounds__(256)
void gather_pack(const int* __restrict__ off, const int* __restrict__ csr_src,
                 const float* __restrict__ h, const float* __restrict__ inv_d,
                 const float* __restrict__ bias, uint32_t* __restrict__ outp, int N)
{
  int node = blockIdx.x * 4 + (threadIdx.x >> 6);
  int lane = threadIdx.x & 63;
  if (node >= N) return;
  float2 acc[3];
  #pragma unroll
  for (int i = 0; i < 3; ++i) acc[i] = {0.f, 0.f};

  int e0 = off[node], e1 = off[node + 1];
  int e = e0;
  for (; e + 4 <= e1; e += 4) {
    const float* r0 = h + (size_t)csr_src[e + 0] * HID;
    const float* r1 = h + (size_t)csr_src[e + 1] * HID;
    const float* r2 = h + (size_t)csr_src[e + 2] * HID;
    const float* r3 = h + (size_t)csr_src[e + 3] * HID;
    #pragma unroll
    for (int i = 0; i < 3; ++i) {
      int f = lane * 2 + i * 128;
      float2 v0 = *(const float2*)&r0[f];
      float2 v1 = *(const float2*)&r1[f];
      float2 v2 = *(const float2*)&r2[f];
      float2 v3 = *(const float2*)&r3[f];
      acc[i].x += (v0.x + v1.x) + (v2.x + v3.x);
      acc[i].y += (v0.y + v1.y) + (v2.y + v3.y);
    }
  }
  for (; e < e1; ++e) {
    const float* hr = h + (size_t)csr_src[e] * HID;
    #pragma unroll
    for (int i = 0; i < 3; ++i) {
      float2 v = *(const float2*)&hr[lane * 2 + i * 128];
      acc[i].x += v.x; acc[i].y += v.y;
    }
  }
  float s = inv_d[node];
  uint32_t* orow = outp + (size_t)node * HID;
  #pragma unroll
  for (int i = 0; i < 3; ++i) {
    int f = lane * 2 + i * 128;
    float vx = fmaxf(fmaf(acc[i].x, s, bias[f]), 0.f);
    float vy = fmaxf(fmaf(acc[i].y, s, bias[f + 1]), 0.f);
    uint2 o = {split_pack(vx), split_pack(vy)};
    *(uint2*)&orow[f] = o;
  }
}

// ---------------------------------------------------------------- CSR gather + classifier fused (4-edge unroll)
__global__ __launch_bounds__(256)
void gather_classifier(const int* __restrict__ off, const int* __restrict__ csr_src,
                       const float* __restrict__ h, const float* __restrict__ inv_d,
                       const float* __restrict__ b2, const float* __restrict__ Wc,
                       const float* __restrict__ bc, float* __restrict__ out, int N)
{
  __shared__ float sWc[EMB * NCLS];
  for (int i = threadIdx.x; i < EMB * NCLS; i += 256) sWc[i] = Wc[i];
  __syncthreads();

  int node = blockIdx.x * 4 + (threadIdx.x >> 6);
  int lane = threadIdx.x & 63;
  if (node >= N) return;

  float2 acc[2] = {{0.f, 0.f}, {0.f, 0.f}};
  int e0 = off[node], e1 = off[node + 1];
  int e = e0;
  for (; e + 4 <= e1; e += 4) {
    const float* r0 = h + (size_t)csr_src[e + 0] * EMB;
    const float* r1 = h + (size_t)csr_src[e + 1] * EMB;
    const float* r2 = h + (size_t)csr_src[e + 2] * EMB;
    const float* r3 = h + (size_t)csr_src[e + 3] * EMB;
    #pragma unroll
    for (int i = 0; i < 2; ++i) {
      int f = lane * 2 + i * 128;
      float2 v0 = *(const float2*)&r0[f];
      float2 v1 = *(const float2*)&r1[f];
      float2 v2 = *(const float2*)&r2[f];
      float2 v3 = *(const float2*)&r3[f];
      acc[i].x += (v0.x + v1.x) + (v2.x + v3.x);
      acc[i].y += (v0.y + v1.y) + (v2.y + v3.y);
    }
  }
  for (; e < e1; ++e) {
    const float* hr = h + (size_t)csr_src[e] * EMB;
    #pragma unroll
    for (int i = 0; i < 2; ++i) {
      float2 v = *(const float2*)&hr[lane * 2 + i * 128];
      acc[i].x += v.x; acc[i].y += v.y;
    }
  }
  float s = inv_d[node];
  float c[NCLS];
  #pragma unroll
  for (int k = 0; k < NCLS; ++k) c[k] = 0.f;
  #pragma unroll
  for (int i = 0; i < 2; ++i) {
    int f = lane * 2 + i * 128;
    float hx = fmaf(acc[i].x, s, b2[f]);
    float hy = fmaf(acc[i].y, s, b2[f + 1]);
    #pragma unroll
    for (int k = 0; k < NCLS; ++k)
      c[k] += hx * sWc[f * NCLS + k] + hy * sWc[(f + 1) * NCLS + k];
  }
  #pragma unroll
  for (int k = 0; k < NCLS; ++k) {
    float v = c[k];
    #pragma unroll
    for (int o = 32; o > 0; o >>= 1) v += __shfl_down(v, o);
    if (lane == 0) out[(size_t)node * NCLS + k] = v + bc[k];
  }
}

// ---------------------------------------------------------------- launch
extern "C" void kernel_launch(void* const* d_in, const int* in_sizes, int n_in,
                              void* d_out, int out_size, void* d_ws, size_t ws_size,
                              hipStream_t stream) {
  const float* features = (const float*)d_in[0];
  const int*   esrc     = (const int*)d_in[1];
  const int*   edst     = (const int*)d_in[2];
  const float* W1       = (const float*)d_in[3];
  const float* b1       = (const float*)d_in[4];
  const float* W2       = (const float*)d_in[5];
  const float* b2       = (const float*)d_in[6];
  const float* Wc       = (const float*)d_in[7];
  const float* bc       = (const float*)d_in[8];
  float* out = (float*)d_out;

  // ---- workspace layout (re-derived every call; ws poisoned 0xAA)
  int* deg_out = (int*)d_ws;                    // 50000
  int* deg_in  = deg_out + NNODES;              // 50000
  int* cursor  = deg_in + NNODES;               // 50000
  int* row_off = cursor + NNODES;               // 50001
  int* csr_src = row_off + NNODES + 1;          // 400000
  int* bsum    = csr_src + NEDGES;              // 196
  int* boff    = bsum + NSB;                    // 196
  float* inv_s = (float*)(boff + NSB);          // 50000
  float* inv_d = inv_s + NNODES;                // 50000
  uintptr_t p16 = ((uintptr_t)(inv_d + NNODES) + 15) & ~(uintptr_t)15;
  uint32_t* hp = (uint32_t*)p16;                // [MP1][HID] packed h
  float* bufA = (float*)(hp + (size_t)MP1 * HID);  // [N,HID] gemm1 out, then [N,EMB] gemm2 out
  char*  Bp1  = (char*)(bufA + (size_t)NNODES * HID);   // 3*45 swizzled 16KB tiles
  char*  Bp2  = Bp1 + (size_t)3 * NKT1 * 16384;         // 2*12 swizzled 16KB tiles

  size_t required = (uintptr_t)(Bp2 + (size_t)2 * NKT2 * 16384) - (uintptr_t)d_ws;
  bool use_mfma = ws_size >= required;

  // ---- graph prep
  hipMemsetAsync(deg_out, 0, 3 * NNODES * sizeof(int), stream);
  degree_kernel<<<1024, 256, 0, stream>>>(esrc, edst, deg_out, deg_in, NEDGES);
  inv_kernel<<<(NNODES + 255) / 256, 256, 0, stream>>>(deg_out, deg_in, inv_s, inv_d, NNODES);
  scan_block<<<NSB, 256, 0, stream>>>(deg_in, row_off, bsum, NNODES);
  scan_tops<<<1, 256, 0, stream>>>(bsum, boff, row_off, NSB, NNODES);
  scan_add<<<NSB, 256, 0, stream>>>(boff, row_off, NNODES);
  fill_csr<<<1024, 256, 0, stream>>>(esrc, edst, row_off, cursor, csr_src, NEDGES);

  if (use_mfma) {
    // ---- layer 1: bufA = inv_s * (X@W1)  (raw-fp32 A staged directly, split in-register)
    convB<INF, HID, NKT1><<<dim3(NKT1, 3), 256, 0, stream>>>(W1, Bp1);
    gemm_mfma<INF * 4, HID, 3, NKT1, true><<<3 * NRB, 256, 0, stream>>>(
        (const char*)features, Bp1, bufA, inv_s);
    gather_pack<<<(NNODES + 3) / 4, 256, 0, stream>>>(
        row_off, csr_src, bufA, inv_d, b1, hp, NNODES);

    // ---- layer 2: bufA = inv_s * (h@W2)   (packed A from gather_pack)
    convB<HID, EMB, NKT2><<<dim3(NKT2, 2), 256, 0, stream>>>(W2, Bp2);
    gemm_mfma<HID * 4, EMB, 2, NKT2, false><<<2 * NRB, 256, 0, stream>>>(
        (const char*)hp, Bp2, bufA, inv_s);
  } else {
    // ---- fallback: full fp32 path
    gemm_scale<16><<<dim3(HID / 128, (NNODES + 127) / 128), 256, 0, stream>>>(
        features, W1, bufA, inv_s, NNODES, HID, INF);
    gather_nodes<HID, true><<<(NNODES + 3) / 4, 256, 0, stream>>>(
        row_off, csr_src, bufA, inv_d, b1, (float*)hp, NNODES);
    gemm_scale<16><<<dim3(EMB / 128, (NNODES + 127) / 128), 256, 0, stream>>>(
        (float*)hp, W2, bufA, inv_s, NNODES, EMB, HID);
  }

  // ---- classifier (fused layer-2 epilogue + gather)
  gather_classifier<<<(NNODES + 3) / 4, 256, 0, stream>>>(
      row_off, csr_src, bufA, inv_d, b2, Wc, bc, out, NNODES);
}